// Round 13
// baseline (856.749 us; speedup 1.0000x reference)
//
#include <hip/hip_runtime.h>

static constexpr int NN = 50000;
static constexpr int NE = 1000000;

typedef short bf16x8 __attribute__((ext_vector_type(8)));
typedef float f32x4 __attribute__((ext_vector_type(4)));

__device__ inline float bf2f_raw(unsigned short u) {
    return __uint_as_float(((unsigned int)u) << 16);
}
__device__ inline unsigned short f2bf(float f) {
    unsigned int u = __float_as_uint(f);
    u += 0x7fffu + ((u >> 16) & 1u);
    return (unsigned short)(u >> 16);
}
__device__ inline void fmax2(float& a0, float& a1, unsigned int v) {
    a0 = fmaxf(a0, bf2f_raw((unsigned short)(v & 0xffffu)));
    a1 = fmaxf(a1, bf2f_raw((unsigned short)(v >> 16)));
}
__device__ inline unsigned int pack2(float f0, float f1) {
    return (unsigned int)f2bf(f0) | ((unsigned int)f2bf(f1) << 16);
}
__device__ inline unsigned int addrelu2(unsigned int a, float t0, float t1) {
    float f0 = fmaxf(bf2f_raw((unsigned short)(a & 0xffffu)) + t0, 0.f);
    float f1 = fmaxf(bf2f_raw((unsigned short)(a >> 16)) + t1, 0.f);
    return pack2(f0, f1);
}

// ---------------- merged setup ----------------

__global__ void setup_kernel(const float* __restrict__ x, const float* __restrict__ W1,
                             const float* __restrict__ b1, const float* __restrict__ b5,
                             const float* __restrict__ W2, const float* __restrict__ W3,
                             const float* __restrict__ W4,
                             unsigned short* __restrict__ as1, float* __restrict__ out,
                             int* __restrict__ deg, int* __restrict__ cursor,
                             int* __restrict__ deghist, int* __restrict__ bincur,
                             unsigned short* __restrict__ Bt2,
                             unsigned short* __restrict__ Bt3,
                             unsigned short* __restrict__ W4t) {
    int t = blockIdx.x * blockDim.x + threadIdx.x;
    if (t < NN * 128) {
        // conv1: as1[i] = [a1(64) | s1(64)],  a = x@(Wt-Wb)+b1, s = x@Wb  (W1 is [6][64])
        int i = t >> 7, c = t & 127;
        float x0 = x[i * 3 + 0], x1 = x[i * 3 + 1], x2 = x[i * 3 + 2];
        float v;
        if (c < 64) {
            v = x0 * (W1[c] - W1[192 + c]) + x1 * (W1[64 + c] - W1[256 + c]) +
                x2 * (W1[128 + c] - W1[320 + c]) + b1[c];
        } else {
            int cs = c - 64;
            v = x0 * W1[192 + cs] + x1 * W1[256 + cs] + x2 * W1[320 + cs];
        }
        as1[t] = f2bf(v);
        return;
    }
    t -= NN * 128;
    if (t < NN * 3) { out[t] = x[t] + b5[t % 3]; return; }
    t -= NN * 3;
    if (t < NN) { deg[t] = 0; return; }
    t -= NN;
    if (t < NN) { cursor[t] = 0; return; }
    t -= NN;
    if (t < 256) { deghist[t] = 0; return; }
    t -= 256;
    if (t < 256) { bincur[t] = 0; return; }
    t -= 256;
    if (t < 8192) {  // W2 split (64x128)
        int k = t / 128, c = t % 128;
        float wt = W2[k * 128 + c];
        float wb = W2[(64 + k) * 128 + c];
        Bt2[c * 64 + k] = f2bf(wt - wb);
        Bt2[(128 + c) * 64 + k] = f2bf(wb);
        return;
    }
    t -= 8192;
    if (t < 65536) {  // W3 split (128x512)
        int k = t / 512, c = t % 512;
        float wt = W3[k * 512 + c];
        float wb = W3[(128 + k) * 512 + c];
        Bt3[c * 128 + k] = f2bf(wt - wb);
        Bt3[(512 + c) * 128 + k] = f2bf(wb);
        return;
    }
    t -= 65536;
    if (t < 131072) {  // W4 transpose (512x256)
        int k = t / 256, n = t % 256;
        W4t[n * 512 + k] = f2bf(W4[k * 256 + n]);
    }
}

// ---------------- CSR build + degree histogram ----------------

__global__ void hist_kernel(const int* __restrict__ dst, int* __restrict__ deg) {
    int e = blockIdx.x * blockDim.x + threadIdx.x;
    if (e < NE) atomicAdd(&deg[dst[e]], 1);
}

__global__ void deghist_kernel(const int* __restrict__ deg, int* __restrict__ deghist) {
    int i = blockIdx.x * blockDim.x + threadIdx.x;
    if (i < NN) {
        int d = deg[i];
        atomicAdd(&deghist[d < 255 ? d : 255], 1);
    }
}

// single-block scan: rowstart over nodes, plus 256-bin degree-histogram scan
__global__ __launch_bounds__(1024) void scan_kernel(const int* __restrict__ deg,
                                                    int* __restrict__ rowstart,
                                                    const int* __restrict__ deghist,
                                                    int* __restrict__ binstart) {
    __shared__ int wave_sums[16];
    __shared__ int bins[256];
    constexpr int CH = (NN + 1023) / 1024;  // 49
    int tid = threadIdx.x;
    int lane = tid & 63;
    int wave = tid >> 6;
    int base = tid * CH;
    int vals[CH];
    int sum = 0;
    #pragma unroll
    for (int i = 0; i < CH; ++i) {
        int idx = base + i;
        vals[i] = (idx < NN) ? deg[idx] : 0;
        sum += vals[i];
    }
    int x = sum;
    #pragma unroll
    for (int off = 1; off < 64; off <<= 1) {
        int y = __shfl_up(x, off);
        if (lane >= off) x += y;
    }
    if (lane == 63) wave_sums[wave] = x;
    if (tid < 256) bins[tid] = deghist[tid];
    __syncthreads();
    if (wave == 0 && lane < 16) {
        int s = wave_sums[lane];
        #pragma unroll
        for (int off = 1; off < 16; off <<= 1) {
            int y = __shfl_up(s, off);
            if (lane >= off) s += y;
        }
        wave_sums[lane] = s;
    }
    if (tid == 1023) {  // serial 256-bin exclusive scan (LDS-resident, ~1us)
        int run2 = 0;
        for (int i = 0; i < 256; ++i) { int v = bins[i]; bins[i] = run2; run2 += v; }
    }
    __syncthreads();
    int run = (wave ? wave_sums[wave - 1] : 0) + x - sum;
    #pragma unroll
    for (int i = 0; i < CH; ++i) {
        int idx = base + i;
        if (idx < NN) rowstart[idx] = run;
        run += vals[i];
    }
    if (tid == 1023) rowstart[NN] = run;
    if (tid < 256) binstart[tid] = bins[tid];
}

// edges -> csr ; nodes -> degree-sorted perm (counting-sort scatter)
__global__ void scatter_kernel(const int* __restrict__ src, const int* __restrict__ dst,
                               const int* __restrict__ rowstart, int* __restrict__ cursor,
                               int* __restrict__ csr, const int* __restrict__ deg,
                               const int* __restrict__ binstart, int* __restrict__ bincur,
                               int* __restrict__ perm) {
    int t = blockIdx.x * blockDim.x + threadIdx.x;
    if (t < NE) {
        int d = dst[t];
        int pos = atomicAdd(&cursor[d], 1);
        csr[rowstart[d] + pos] = src[t];
    } else if (t < NE + NN) {
        int i = t - NE;
        int d = deg[i];
        if (d > 255) d = 255;
        int pos = atomicAdd(&bincur[d], 1);
        perm[binstart[d] + pos] = i;
    }
}

// ---------------- conv1 fused edge-max + epilogue (C=64, as rows [a(64)|s(64)]) ----------------

__global__ __launch_bounds__(256) void edge_fused_conv1_kernel(
    const unsigned short* __restrict__ as, const int* __restrict__ rowstart,
    const int* __restrict__ csr, unsigned short* __restrict__ x1) {
    int wid = (blockIdx.x * 256 + threadIdx.x) >> 6;
    int lane = threadIdx.x & 63;
    if (wid >= NN) return;
    int e0 = __builtin_amdgcn_readfirstlane(rowstart[wid]);
    int e1 = __builtin_amdgcn_readfirstlane(rowstart[wid + 1]);
    int h = lane >> 5, c0 = (lane & 31) * 2;
    float t0 = -INFINITY, t1 = -INFINITY;
    const unsigned short* sb = as + 64 + c0;
    int nedge = e1 - e0;
    for (int base = 0; base < nedge; base += 64) {
        int rem = nedge - base;
        int myj = csr[(lane < rem) ? (e0 + base + lane) : e0];
        int cnt = rem < 64 ? rem : 64;
        int cp = (cnt + 7) & ~7;
        for (int q = 0; q < cp; q += 8) {
            int j0 = __shfl(myj, q + 0 + h);
            int j1 = __shfl(myj, q + 2 + h);
            int j2 = __shfl(myj, q + 4 + h);
            int j3 = __shfl(myj, q + 6 + h);
            unsigned int v0 = *(const unsigned int*)(sb + (size_t)j0 * 128);
            unsigned int v1 = *(const unsigned int*)(sb + (size_t)j1 * 128);
            unsigned int v2 = *(const unsigned int*)(sb + (size_t)j2 * 128);
            unsigned int v3 = *(const unsigned int*)(sb + (size_t)j3 * 128);
            fmax2(t0, t1, v0);
            fmax2(t0, t1, v1);
            fmax2(t0, t1, v2);
            fmax2(t0, t1, v3);
        }
    }
    t0 = fmaxf(t0, __shfl_xor(t0, 32));
    t1 = fmaxf(t1, __shfl_xor(t1, 32));
    if (h == 0) {
        unsigned int av = *(const unsigned int*)(as + (size_t)wid * 128 + c0);
        *(unsigned int*)(x1 + (size_t)wid * 64 + c0) = addrelu2(av, t0, t1);
    }
}

// ---------------- fused edge-max + epilogue, C=128 (as rows [a(128)|s(128)]) ----------------

__global__ __launch_bounds__(256) void edge_fused128_kernel(
    const unsigned short* __restrict__ as, const int* __restrict__ rowstart,
    const int* __restrict__ csr, unsigned short* __restrict__ xout) {
    int wid = (blockIdx.x * 256 + threadIdx.x) >> 6;
    int lane = threadIdx.x & 63;
    if (wid >= NN) return;
    int e0 = __builtin_amdgcn_readfirstlane(rowstart[wid]);
    int e1 = __builtin_amdgcn_readfirstlane(rowstart[wid + 1]);
    float t0 = -INFINITY, t1 = -INFINITY;
    const unsigned short* sb = as + 128 + (size_t)lane * 2;
    int nedge = e1 - e0;
    for (int base = 0; base < nedge; base += 64) {
        int rem = nedge - base;
        int myj = csr[(lane < rem) ? (e0 + base + lane) : e0];
        int cnt = rem < 64 ? rem : 64;
        int cp = (cnt + 7) & ~7;
        for (int q = 0; q < cp; q += 8) {
            int j0 = __shfl(myj, q + 0), j1 = __shfl(myj, q + 1);
            int j2 = __shfl(myj, q + 2), j3 = __shfl(myj, q + 3);
            int j4 = __shfl(myj, q + 4), j5 = __shfl(myj, q + 5);
            int j6 = __shfl(myj, q + 6), j7 = __shfl(myj, q + 7);
            unsigned int v0 = *(const unsigned int*)(sb + (size_t)j0 * 256);
            unsigned int v1 = *(const unsigned int*)(sb + (size_t)j1 * 256);
            unsigned int v2 = *(const unsigned int*)(sb + (size_t)j2 * 256);
            unsigned int v3 = *(const unsigned int*)(sb + (size_t)j3 * 256);
            unsigned int v4 = *(const unsigned int*)(sb + (size_t)j4 * 256);
            unsigned int v5 = *(const unsigned int*)(sb + (size_t)j5 * 256);
            unsigned int v6 = *(const unsigned int*)(sb + (size_t)j6 * 256);
            unsigned int v7 = *(const unsigned int*)(sb + (size_t)j7 * 256);
            fmax2(t0, t1, v0); fmax2(t0, t1, v1);
            fmax2(t0, t1, v2); fmax2(t0, t1, v3);
            fmax2(t0, t1, v4); fmax2(t0, t1, v5);
            fmax2(t0, t1, v6); fmax2(t0, t1, v7);
        }
    }
    unsigned int av = *(const unsigned int*)(as + (size_t)wid * 256 + lane * 2);
    *(unsigned int*)(xout + (size_t)wid * 128 + lane * 2) = addrelu2(av, t0, t1);
}

// ---------------- fused ef512 + h4-GEMM + W5 (256 thr, 4 waves x 4 nodes, degree-sorted) --------
// Block = 16 degree-matched nodes via perm -> slowest-of-16 barrier waste ~0.

__global__ __launch_bounds__(256) void ef512_w5_kernel(
    const unsigned short* __restrict__ as, const int* __restrict__ rowstart,
    const int* __restrict__ csr, const int* __restrict__ perm,
    const unsigned short* __restrict__ W4t,
    const float* __restrict__ b4, const float* __restrict__ W5,
    float* __restrict__ out) {
    __shared__ __align__(16) unsigned short X[16][520];  // x3 tile, +8 pad
    __shared__ int nid[16];
    int wave = threadIdx.x >> 6, lane = threadIdx.x & 63;
    int tilebase = blockIdx.x * 16;

    // ---- gather phase: this wave builds rows wave*4 .. wave*4+3 ----
    const unsigned short* sb = as + 512 + (size_t)lane * 8;
    for (int i = 0; i < 4; ++i) {
        int trow = wave * 4 + i;
        int node = __builtin_amdgcn_readfirstlane(perm[tilebase + trow]);
        if (lane == 0) nid[trow] = node;
        int e0 = __builtin_amdgcn_readfirstlane(rowstart[node]);
        int e1 = __builtin_amdgcn_readfirstlane(rowstart[node + 1]);
        float acc[8];
        #pragma unroll
        for (int v = 0; v < 8; ++v) acc[v] = -INFINITY;
        int nedge = e1 - e0;
        for (int base = 0; base < nedge; base += 64) {
            int rem = nedge - base;
            int myj = csr[(lane < rem) ? (e0 + base + lane) : e0];
            int cnt = rem < 64 ? rem : 64;
            int cp = (cnt + 3) & ~3;
            for (int q = 0; q < cp; q += 4) {
                int j0 = __shfl(myj, q + 0), j1 = __shfl(myj, q + 1);
                int j2 = __shfl(myj, q + 2), j3 = __shfl(myj, q + 3);
                uint4 v0 = *(const uint4*)(sb + (size_t)j0 * 1024);
                uint4 v1 = *(const uint4*)(sb + (size_t)j1 * 1024);
                uint4 v2 = *(const uint4*)(sb + (size_t)j2 * 1024);
                uint4 v3 = *(const uint4*)(sb + (size_t)j3 * 1024);
                fmax2(acc[0], acc[1], v0.x); fmax2(acc[2], acc[3], v0.y);
                fmax2(acc[4], acc[5], v0.z); fmax2(acc[6], acc[7], v0.w);
                fmax2(acc[0], acc[1], v1.x); fmax2(acc[2], acc[3], v1.y);
                fmax2(acc[4], acc[5], v1.z); fmax2(acc[6], acc[7], v1.w);
                fmax2(acc[0], acc[1], v2.x); fmax2(acc[2], acc[3], v2.y);
                fmax2(acc[4], acc[5], v2.z); fmax2(acc[6], acc[7], v2.w);
                fmax2(acc[0], acc[1], v3.x); fmax2(acc[2], acc[3], v3.y);
                fmax2(acc[4], acc[5], v3.z); fmax2(acc[6], acc[7], v3.w);
            }
        }
        uint4 av = *(const uint4*)(as + (size_t)node * 1024 + lane * 8);
        uint4 o;
        o.x = addrelu2(av.x, acc[0], acc[1]);
        o.y = addrelu2(av.y, acc[2], acc[3]);
        o.z = addrelu2(av.z, acc[4], acc[5]);
        o.w = addrelu2(av.w, acc[6], acc[7]);
        *(uint4*)&X[trow][lane * 8] = o;
    }
    __syncthreads();

    // ---- MFMA phase: wave handles cols [wave*64, wave*64+64) of h (N=256) ----
    int quad = lane >> 4, l16 = lane & 15;
    int colbase = wave * 64;
    f32x4 acc4[4] = {};
    for (int kc = 0; kc < 16; ++kc) {
        bf16x8 afr = *(const bf16x8*)&X[l16][kc * 32 + quad * 8];
        #pragma unroll
        for (int nt = 0; nt < 4; ++nt) {
            int col = colbase + nt * 16 + l16;
            bf16x8 bfr = *(const bf16x8*)&W4t[(size_t)col * 512 + kc * 32 + quad * 8];
            acc4[nt] = __builtin_amdgcn_mfma_f32_16x16x32_bf16(afr, bfr, acc4[nt], 0, 0, 0);
        }
    }
    // ---- epilogue: h = relu(acc + b4); out += h @ W5 ----
    float b4v[4], w5r[4][3];
    #pragma unroll
    for (int nt = 0; nt < 4; ++nt) {
        int col = colbase + nt * 16 + l16;
        b4v[nt] = b4[col];
        w5r[nt][0] = W5[col * 3 + 0];
        w5r[nt][1] = W5[col * 3 + 1];
        w5r[nt][2] = W5[col * 3 + 2];
    }
    #pragma unroll
    for (int r = 0; r < 4; ++r) {
        int row = nid[quad * 4 + r];
        float p0 = 0.f, p1 = 0.f, p2 = 0.f;
        #pragma unroll
        for (int nt = 0; nt < 4; ++nt) {
            float h = fmaxf(acc4[nt][r] + b4v[nt], 0.f);
            p0 += h * w5r[nt][0];
            p1 += h * w5r[nt][1];
            p2 += h * w5r[nt][2];
        }
        #pragma unroll
        for (int m = 8; m; m >>= 1) {
            p0 += __shfl_xor(p0, m);
            p1 += __shfl_xor(p1, m);
            p2 += __shfl_xor(p2, m);
        }
        if (l16 == 0) {
            atomicAdd(&out[row * 3 + 0], p0);
            atomicAdd(&out[row * 3 + 1], p1);
            atomicAdd(&out[row * 3 + 2], p2);
        }
    }
}

// ---------------- N-loop MFMA GEMM: A staged in LDS ONCE, loop over N-tiles ----------------

template<int K, int NT>
__global__ __launch_bounds__(256) void mfma_gemm_nloop_kernel(
    const unsigned short* __restrict__ A, const unsigned short* __restrict__ Bt,
    const float* __restrict__ bias, int bias_n,
    unsigned short* __restrict__ C, int M) {
    constexpr int KC = K / 32;       // k-chunks
    constexpr int N = NT * 128;
    __shared__ __align__(16) unsigned short Asl[KC][128 * 40];
    __shared__ __align__(16) unsigned short Bsl[128 * 40];
    int tid = threadIdx.x;
    int mbase = blockIdx.x * 128;
    int wave = tid >> 6, lane = tid & 63;
    int wm = (wave >> 1) * 64, wn = (wave & 1) * 64;
    int quad = lane >> 4, l16 = lane & 15;

    // stage ALL of A once: KC*512 chunks of 16B
    #pragma unroll
    for (int c = tid; c < KC * 512; c += 256) {
        int kc = c >> 9, rem = c & 511;
        int r = rem >> 2, kk = (rem & 3) * 8;
        uint4 va = make_uint4(0u, 0u, 0u, 0u);
        int gr = mbase + r;
        if (gr < M) va = *(const uint4*)&A[(size_t)gr * K + kc * 32 + kk];
        *(uint4*)&Asl[kc][r * 40 + kk] = va;
    }

    for (int nt = 0; nt < NT; ++nt) {
        int nbase = nt * 128;
        f32x4 acc[4][4] = {};
        for (int kc = 0; kc < KC; ++kc) {
            __syncthreads();
            #pragma unroll
            for (int h = 0; h < 2; ++h) {
                int c = tid + h * 256;
                int r = c >> 2, kk = (c & 3) * 8;
                uint4 vb = *(const uint4*)&Bt[(size_t)(nbase + r) * K + kc * 32 + kk];
                *(uint4*)&Bsl[r * 40 + kk] = vb;
            }
            __syncthreads();
            bf16x8 af[4], bfr[4];
            #pragma unroll
            for (int tt = 0; tt < 4; ++tt) {
                af[tt]  = *(const bf16x8*)&Asl[kc][(wm + tt * 16 + l16) * 40 + quad * 8];
                bfr[tt] = *(const bf16x8*)&Bsl[(wn + tt * 16 + l16) * 40 + quad * 8];
            }
            #pragma unroll
            for (int mt = 0; mt < 4; ++mt)
                #pragma unroll
                for (int ntt = 0; ntt < 4; ++ntt)
                    acc[mt][ntt] = __builtin_amdgcn_mfma_f32_16x16x32_bf16(
                        af[mt], bfr[ntt], acc[mt][ntt], 0, 0, 0);
        }
        #pragma unroll
        for (int mt = 0; mt < 4; ++mt) {
            #pragma unroll
            for (int r = 0; r < 4; ++r) {
                int row = mbase + wm + mt * 16 + quad * 4 + r;
                if (row >= M) continue;
                #pragma unroll
                for (int ntt = 0; ntt < 4; ++ntt) {
                    int col = nbase + wn + ntt * 16 + l16;
                    float v = acc[mt][ntt][r];
                    if (col < bias_n) v += bias[col];
                    C[(size_t)row * N + col] = f2bf(v);
                }
            }
        }
    }
}

__global__ void fallback_copy_kernel(const float* __restrict__ x, float* __restrict__ out) {
    int t = blockIdx.x * blockDim.x + threadIdx.x;
    if (t < NN * 3) out[t] = x[t];
}

// ---------------- launcher ----------------

extern "C" void kernel_launch(void* const* d_in, const int* in_sizes, int n_in,
                              void* d_out, int out_size, void* d_ws, size_t ws_size,
                              hipStream_t stream) {
    const float* x  = (const float*)d_in[0];
    const int*   ei = (const int*)d_in[1];
    const float* W1 = (const float*)d_in[2];
    const float* b1 = (const float*)d_in[3];
    const float* W2 = (const float*)d_in[4];
    const float* b2 = (const float*)d_in[5];
    const float* W3 = (const float*)d_in[6];
    const float* b3 = (const float*)d_in[7];
    const float* W4 = (const float*)d_in[8];
    const float* b4 = (const float*)d_in[9];
    const float* W5 = (const float*)d_in[10];
    const float* b5 = (const float*)d_in[11];
    float* out = (float*)d_out;

    char* p = (char*)d_ws;
    auto alloc = [&](size_t bytes) -> void* {
        void* r = (void*)p;
        p += (bytes + 255) & ~(size_t)255;
        return r;
    };
    int* deg      = (int*)alloc((size_t)NN * 4);
    int* rowstart = (int*)alloc((size_t)(NN + 1) * 4);
    int* cursor   = (int*)alloc((size_t)NN * 4);
    int* csr      = (int*)alloc((size_t)NE * 4);
    int* perm     = (int*)alloc((size_t)NN * 4);
    int* deghist  = (int*)alloc(256 * 4);
    int* binstart = (int*)alloc(256 * 4);
    int* bincur   = (int*)alloc(256 * 4);
    unsigned short* Bt2 = (unsigned short*)alloc(256 * 64 * 2);
    unsigned short* Bt3 = (unsigned short*)alloc(1024 * 128 * 2);
    unsigned short* W4t = (unsigned short*)alloc(256 * 512 * 2);
    unsigned short* x1 = (unsigned short*)alloc((size_t)NN * 64 * 2);
    unsigned short* x2 = (unsigned short*)alloc((size_t)NN * 128 * 2);
    unsigned short* as_slab = (unsigned short*)alloc((size_t)NN * 1024 * 2);  // as1/as2/as3
    size_t need = (size_t)(p - (char*)d_ws);
    if (ws_size < need) {
        fallback_copy_kernel<<<(NN * 3 + 255) / 256, 256, 0, stream>>>(x, out);
        return;
    }

    const int* src = ei;        // edge_index[0]
    const int* dst = ei + NE;   // edge_index[1]

    // merged setup (one dispatch)
    constexpr int SETUP_T = NN * 128 + NN * 3 + NN + NN + 256 + 256 + 8192 + 65536 + 131072;
    setup_kernel<<<(SETUP_T + 255) / 256, 256, 0, stream>>>(
        x, W1, b1, b5, W2, W3, W4, as_slab, out, deg, cursor, deghist, bincur,
        Bt2, Bt3, W4t);

    // CSR by dst + degree-sorted node permutation
    hist_kernel<<<(NE + 255) / 256, 256, 0, stream>>>(dst, deg);
    deghist_kernel<<<(NN + 255) / 256, 256, 0, stream>>>(deg, deghist);
    scan_kernel<<<1, 1024, 0, stream>>>(deg, rowstart, deghist, binstart);
    scatter_kernel<<<(NE + NN + 255) / 256, 256, 0, stream>>>(
        src, dst, rowstart, cursor, csr, deg, binstart, bincur, perm);

    // conv1: x1 = relu(a1 + max_j s1[j])
    edge_fused_conv1_kernel<<<12500, 256, 0, stream>>>(as_slab, rowstart, csr, x1);

    // conv2: as2 = x1 @ [Wtb2|Wb2] (+b2 on a-half); x2 = relu(a2 + max s2)
    mfma_gemm_nloop_kernel<64, 2><<<391, 256, 0, stream>>>(
        x1, Bt2, b2, 128, as_slab, NN);
    edge_fused128_kernel<<<12500, 256, 0, stream>>>(as_slab, rowstart, csr, x2);

    // conv3: as3 = x2 @ [Wtb3|Wb3] (+b3 on a-half)
    mfma_gemm_nloop_kernel<128, 8><<<391, 256, 0, stream>>>(
        x2, Bt3, b3, 512, as_slab, NN);

    // fused: degree-matched 16-node tiles -> h = relu(X@W4+b4) -> out += h@W5
    ef512_w5_kernel<<<NN / 16, 256, 0, stream>>>(
        as_slab, rowstart, csr, perm, W4t, b4, W5, out);
}

// Round 14
// 623.715 us; speedup vs baseline: 1.3736x; 1.3736x over previous
//
#include <hip/hip_runtime.h>

static constexpr int NN = 50000;
static constexpr int NE = 1000000;

typedef short bf16x8 __attribute__((ext_vector_type(8)));
typedef float f32x4 __attribute__((ext_vector_type(4)));

__device__ inline float bf2f_raw(unsigned short u) {
    return __uint_as_float(((unsigned int)u) << 16);
}
__device__ inline unsigned short f2bf(float f) {
    unsigned int u = __float_as_uint(f);
    u += 0x7fffu + ((u >> 16) & 1u);
    return (unsigned short)(u >> 16);
}
__device__ inline void fmax2(float& a0, float& a1, unsigned int v) {
    a0 = fmaxf(a0, bf2f_raw((unsigned short)(v & 0xffffu)));
    a1 = fmaxf(a1, bf2f_raw((unsigned short)(v >> 16)));
}
__device__ inline unsigned int pack2(float f0, float f1) {
    return (unsigned int)f2bf(f0) | ((unsigned int)f2bf(f1) << 16);
}
__device__ inline unsigned int addrelu2(unsigned int a, float t0, float t1) {
    float f0 = fmaxf(bf2f_raw((unsigned short)(a & 0xffffu)) + t0, 0.f);
    float f1 = fmaxf(bf2f_raw((unsigned short)(a >> 16)) + t1, 0.f);
    return pack2(f0, f1);
}

// ---------------- merged setup: conv1_as + out-init + deg-zero + cursor-zero + weight prep --------

__global__ void setup_kernel(const float* __restrict__ x, const float* __restrict__ W1,
                             const float* __restrict__ b1, const float* __restrict__ b5,
                             const float* __restrict__ W2, const float* __restrict__ W3,
                             const float* __restrict__ W4,
                             unsigned short* __restrict__ as1, float* __restrict__ out,
                             int* __restrict__ deg, int* __restrict__ cursor,
                             unsigned short* __restrict__ Bt2,
                             unsigned short* __restrict__ Bt3,
                             unsigned short* __restrict__ W4t) {
    int t = blockIdx.x * blockDim.x + threadIdx.x;
    if (t < NN * 128) {
        // conv1: as1[i] = [a1(64) | s1(64)],  a = x@(Wt-Wb)+b1, s = x@Wb  (W1 is [6][64])
        int i = t >> 7, c = t & 127;
        float x0 = x[i * 3 + 0], x1 = x[i * 3 + 1], x2 = x[i * 3 + 2];
        float v;
        if (c < 64) {
            v = x0 * (W1[c] - W1[192 + c]) + x1 * (W1[64 + c] - W1[256 + c]) +
                x2 * (W1[128 + c] - W1[320 + c]) + b1[c];
        } else {
            int cs = c - 64;
            v = x0 * W1[192 + cs] + x1 * W1[256 + cs] + x2 * W1[320 + cs];
        }
        as1[t] = f2bf(v);
        return;
    }
    t -= NN * 128;
    if (t < NN * 3) { out[t] = x[t] + b5[t % 3]; return; }
    t -= NN * 3;
    if (t < NN) { deg[t] = 0; return; }
    t -= NN;
    if (t < NN) { cursor[t] = 0; return; }
    t -= NN;
    if (t < 8192) {  // W2 split (64x128)
        int k = t / 128, c = t % 128;
        float wt = W2[k * 128 + c];
        float wb = W2[(64 + k) * 128 + c];
        Bt2[c * 64 + k] = f2bf(wt - wb);
        Bt2[(128 + c) * 64 + k] = f2bf(wb);
        return;
    }
    t -= 8192;
    if (t < 65536) {  // W3 split (128x512)
        int k = t / 512, c = t % 512;
        float wt = W3[k * 512 + c];
        float wb = W3[(128 + k) * 512 + c];
        Bt3[c * 128 + k] = f2bf(wt - wb);
        Bt3[(512 + c) * 128 + k] = f2bf(wb);
        return;
    }
    t -= 65536;
    if (t < 131072) {  // W4 transpose (512x256)
        int k = t / 256, n = t % 256;
        W4t[n * 512 + k] = f2bf(W4[k * 256 + n]);
    }
}

// ---------------- CSR build ----------------

__global__ void hist_kernel(const int* __restrict__ dst, int* __restrict__ deg) {
    int e = blockIdx.x * blockDim.x + threadIdx.x;
    if (e < NE) atomicAdd(&deg[dst[e]], 1);
}

// single-block scan, register-resident
__global__ __launch_bounds__(1024) void scan_kernel(const int* __restrict__ deg,
                                                    int* __restrict__ rowstart) {
    __shared__ int wave_sums[16];
    constexpr int CH = (NN + 1023) / 1024;  // 49
    int tid = threadIdx.x;
    int lane = tid & 63;
    int wave = tid >> 6;
    int base = tid * CH;
    int vals[CH];
    int sum = 0;
    #pragma unroll
    for (int i = 0; i < CH; ++i) {
        int idx = base + i;
        vals[i] = (idx < NN) ? deg[idx] : 0;
        sum += vals[i];
    }
    int x = sum;
    #pragma unroll
    for (int off = 1; off < 64; off <<= 1) {
        int y = __shfl_up(x, off);
        if (lane >= off) x += y;
    }
    if (lane == 63) wave_sums[wave] = x;
    __syncthreads();
    if (wave == 0 && lane < 16) {
        int s = wave_sums[lane];
        #pragma unroll
        for (int off = 1; off < 16; off <<= 1) {
            int y = __shfl_up(s, off);
            if (lane >= off) s += y;
        }
        wave_sums[lane] = s;
    }
    __syncthreads();
    int run = (wave ? wave_sums[wave - 1] : 0) + x - sum;
    #pragma unroll
    for (int i = 0; i < CH; ++i) {
        int idx = base + i;
        if (idx < NN) rowstart[idx] = run;
        run += vals[i];
    }
    if (tid == 1023) rowstart[NN] = run;
}

__global__ void scatter_kernel(const int* __restrict__ src, const int* __restrict__ dst,
                               const int* __restrict__ rowstart, int* __restrict__ cursor,
                               int* __restrict__ csr) {
    int e = blockIdx.x * blockDim.x + threadIdx.x;
    if (e < NE) {
        int d = dst[e];
        int pos = atomicAdd(&cursor[d], 1);
        csr[rowstart[d] + pos] = src[e];
    }
}

// ---------------- conv1 fused edge-max + epilogue (C=64, as rows [a(64)|s(64)]) ----------------

__global__ __launch_bounds__(256) void edge_fused_conv1_kernel(
    const unsigned short* __restrict__ as, const int* __restrict__ rowstart,
    const int* __restrict__ csr, unsigned short* __restrict__ x1) {
    int wid = (blockIdx.x * 256 + threadIdx.x) >> 6;
    int lane = threadIdx.x & 63;
    if (wid >= NN) return;
    int e0 = __builtin_amdgcn_readfirstlane(rowstart[wid]);
    int e1 = __builtin_amdgcn_readfirstlane(rowstart[wid + 1]);
    int h = lane >> 5, c0 = (lane & 31) * 2;
    float t0 = -INFINITY, t1 = -INFINITY;
    const unsigned short* sb = as + 64 + c0;
    int nedge = e1 - e0;
    for (int base = 0; base < nedge; base += 64) {
        int rem = nedge - base;
        int myj = csr[(lane < rem) ? (e0 + base + lane) : e0];
        int cnt = rem < 64 ? rem : 64;
        int cp = (cnt + 7) & ~7;
        for (int q = 0; q < cp; q += 8) {
            int j0 = __shfl(myj, q + 0 + h);
            int j1 = __shfl(myj, q + 2 + h);
            int j2 = __shfl(myj, q + 4 + h);
            int j3 = __shfl(myj, q + 6 + h);
            unsigned int v0 = *(const unsigned int*)(sb + (size_t)j0 * 128);
            unsigned int v1 = *(const unsigned int*)(sb + (size_t)j1 * 128);
            unsigned int v2 = *(const unsigned int*)(sb + (size_t)j2 * 128);
            unsigned int v3 = *(const unsigned int*)(sb + (size_t)j3 * 128);
            fmax2(t0, t1, v0);
            fmax2(t0, t1, v1);
            fmax2(t0, t1, v2);
            fmax2(t0, t1, v3);
        }
    }
    t0 = fmaxf(t0, __shfl_xor(t0, 32));
    t1 = fmaxf(t1, __shfl_xor(t1, 32));
    if (h == 0) {
        unsigned int av = *(const unsigned int*)(as + (size_t)wid * 128 + c0);
        *(unsigned int*)(x1 + (size_t)wid * 64 + c0) = addrelu2(av, t0, t1);
    }
}

// ---------------- fused edge-max + epilogue, C=128 (as rows [a(128)|s(128)]) ----------------

__global__ __launch_bounds__(256) void edge_fused128_kernel(
    const unsigned short* __restrict__ as, const int* __restrict__ rowstart,
    const int* __restrict__ csr, unsigned short* __restrict__ xout) {
    int wid = (blockIdx.x * 256 + threadIdx.x) >> 6;
    int lane = threadIdx.x & 63;
    if (wid >= NN) return;
    int e0 = __builtin_amdgcn_readfirstlane(rowstart[wid]);
    int e1 = __builtin_amdgcn_readfirstlane(rowstart[wid + 1]);
    float t0 = -INFINITY, t1 = -INFINITY;
    const unsigned short* sb = as + 128 + (size_t)lane * 2;
    int nedge = e1 - e0;
    for (int base = 0; base < nedge; base += 64) {
        int rem = nedge - base;
        int myj = csr[(lane < rem) ? (e0 + base + lane) : e0];
        int cnt = rem < 64 ? rem : 64;
        int cp = (cnt + 7) & ~7;
        for (int q = 0; q < cp; q += 8) {
            int j0 = __shfl(myj, q + 0), j1 = __shfl(myj, q + 1);
            int j2 = __shfl(myj, q + 2), j3 = __shfl(myj, q + 3);
            int j4 = __shfl(myj, q + 4), j5 = __shfl(myj, q + 5);
            int j6 = __shfl(myj, q + 6), j7 = __shfl(myj, q + 7);
            unsigned int v0 = *(const unsigned int*)(sb + (size_t)j0 * 256);
            unsigned int v1 = *(const unsigned int*)(sb + (size_t)j1 * 256);
            unsigned int v2 = *(const unsigned int*)(sb + (size_t)j2 * 256);
            unsigned int v3 = *(const unsigned int*)(sb + (size_t)j3 * 256);
            unsigned int v4 = *(const unsigned int*)(sb + (size_t)j4 * 256);
            unsigned int v5 = *(const unsigned int*)(sb + (size_t)j5 * 256);
            unsigned int v6 = *(const unsigned int*)(sb + (size_t)j6 * 256);
            unsigned int v7 = *(const unsigned int*)(sb + (size_t)j7 * 256);
            fmax2(t0, t1, v0); fmax2(t0, t1, v1);
            fmax2(t0, t1, v2); fmax2(t0, t1, v3);
            fmax2(t0, t1, v4); fmax2(t0, t1, v5);
            fmax2(t0, t1, v6); fmax2(t0, t1, v7);
        }
    }
    unsigned int av = *(const unsigned int*)(as + (size_t)wid * 256 + lane * 2);
    *(unsigned int*)(xout + (size_t)wid * 128 + lane * 2) = addrelu2(av, t0, t1);
}

// ---------------- fused ef512 + h4-GEMM + W5 (256 thr, 4 waves x 4 nodes, PAIRED gather) --------
// Each wave gathers TWO nodes concurrently (independent load streams, one drain per pair).
// Out-of-range lanes/steps re-read the node's first neighbor (idempotent under max);
// wave-uniform nA==0 guard keeps degree-0 semantics exact.

__global__ __launch_bounds__(256) void ef512_w5_kernel(
    const unsigned short* __restrict__ as, const int* __restrict__ rowstart,
    const int* __restrict__ csr, const unsigned short* __restrict__ W4t,
    const float* __restrict__ b4, const float* __restrict__ W5,
    float* __restrict__ out) {
    __shared__ __align__(16) unsigned short X[16][520];  // x3 tile, +8 pad
    int wave = threadIdx.x >> 6, lane = threadIdx.x & 63;
    int tilebase = blockIdx.x * 16;
    const unsigned short* sb = as + 512 + (size_t)lane * 8;

    for (int i = 0; i < 4; i += 2) {
        int nodeA = tilebase + wave * 4 + i;
        int nodeB = nodeA + 1;
        int a0 = __builtin_amdgcn_readfirstlane(rowstart[nodeA]);
        int a1 = __builtin_amdgcn_readfirstlane(rowstart[nodeA + 1]);
        int b0 = a1;
        int b1 = __builtin_amdgcn_readfirstlane(rowstart[nodeB + 1]);
        float accA[8], accB[8];
        #pragma unroll
        for (int v = 0; v < 8; ++v) { accA[v] = -INFINITY; accB[v] = -INFINITY; }
        int nA = a1 - a0, nB = b1 - b0;
        int nmax = nA > nB ? nA : nB;
        for (int base = 0; base < nmax; base += 64) {
            int rA = nA - base, rB = nB - base;
            int myjA = csr[(lane < rA) ? (a0 + base + lane) : a0];
            int myjB = csr[(lane < rB) ? (b0 + base + lane) : b0];
            int cA = rA < 64 ? (rA < 0 ? 0 : rA) : 64;
            int cB = rB < 64 ? (rB < 0 ? 0 : rB) : 64;
            int cmax = cA > cB ? cA : cB;
            int cp = (cmax + 3) & ~3;
            for (int q = 0; q < cp; q += 4) {
                int jA0 = __shfl(myjA, q + 0), jA1 = __shfl(myjA, q + 1);
                int jA2 = __shfl(myjA, q + 2), jA3 = __shfl(myjA, q + 3);
                int jB0 = __shfl(myjB, q + 0), jB1 = __shfl(myjB, q + 1);
                int jB2 = __shfl(myjB, q + 2), jB3 = __shfl(myjB, q + 3);
                uint4 vA0 = *(const uint4*)(sb + (size_t)jA0 * 1024);
                uint4 vA1 = *(const uint4*)(sb + (size_t)jA1 * 1024);
                uint4 vA2 = *(const uint4*)(sb + (size_t)jA2 * 1024);
                uint4 vA3 = *(const uint4*)(sb + (size_t)jA3 * 1024);
                uint4 vB0 = *(const uint4*)(sb + (size_t)jB0 * 1024);
                uint4 vB1 = *(const uint4*)(sb + (size_t)jB1 * 1024);
                uint4 vB2 = *(const uint4*)(sb + (size_t)jB2 * 1024);
                uint4 vB3 = *(const uint4*)(sb + (size_t)jB3 * 1024);
                fmax2(accA[0], accA[1], vA0.x); fmax2(accA[2], accA[3], vA0.y);
                fmax2(accA[4], accA[5], vA0.z); fmax2(accA[6], accA[7], vA0.w);
                fmax2(accA[0], accA[1], vA1.x); fmax2(accA[2], accA[3], vA1.y);
                fmax2(accA[4], accA[5], vA1.z); fmax2(accA[6], accA[7], vA1.w);
                fmax2(accA[0], accA[1], vA2.x); fmax2(accA[2], accA[3], vA2.y);
                fmax2(accA[4], accA[5], vA2.z); fmax2(accA[6], accA[7], vA2.w);
                fmax2(accA[0], accA[1], vA3.x); fmax2(accA[2], accA[3], vA3.y);
                fmax2(accA[4], accA[5], vA3.z); fmax2(accA[6], accA[7], vA3.w);
                fmax2(accB[0], accB[1], vB0.x); fmax2(accB[2], accB[3], vB0.y);
                fmax2(accB[4], accB[5], vB0.z); fmax2(accB[6], accB[7], vB0.w);
                fmax2(accB[0], accB[1], vB1.x); fmax2(accB[2], accB[3], vB1.y);
                fmax2(accB[4], accB[5], vB1.z); fmax2(accB[6], accB[7], vB1.w);
                fmax2(accB[0], accB[1], vB2.x); fmax2(accB[2], accB[3], vB2.y);
                fmax2(accB[4], accB[5], vB2.z); fmax2(accB[6], accB[7], vB2.w);
                fmax2(accB[0], accB[1], vB3.x); fmax2(accB[2], accB[3], vB3.y);
                fmax2(accB[4], accB[5], vB3.z); fmax2(accB[6], accB[7], vB3.w);
            }
        }
        if (nA == 0) {
            #pragma unroll
            for (int v = 0; v < 8; ++v) accA[v] = -INFINITY;
        }
        if (nB == 0) {
            #pragma unroll
            for (int v = 0; v < 8; ++v) accB[v] = -INFINITY;
        }
        uint4 avA = *(const uint4*)(as + (size_t)nodeA * 1024 + lane * 8);
        uint4 avB = *(const uint4*)(as + (size_t)nodeB * 1024 + lane * 8);
        uint4 oA, oB;
        oA.x = addrelu2(avA.x, accA[0], accA[1]);
        oA.y = addrelu2(avA.y, accA[2], accA[3]);
        oA.z = addrelu2(avA.z, accA[4], accA[5]);
        oA.w = addrelu2(avA.w, accA[6], accA[7]);
        oB.x = addrelu2(avB.x, accB[0], accB[1]);
        oB.y = addrelu2(avB.y, accB[2], accB[3]);
        oB.z = addrelu2(avB.z, accB[4], accB[5]);
        oB.w = addrelu2(avB.w, accB[6], accB[7]);
        *(uint4*)&X[wave * 4 + i][lane * 8] = oA;
        *(uint4*)&X[wave * 4 + i + 1][lane * 8] = oB;
    }
    __syncthreads();

    // ---- MFMA phase: wave handles cols [wave*64, wave*64+64) of h (N=256) ----
    int quad = lane >> 4, l16 = lane & 15;
    int colbase = wave * 64;
    f32x4 acc4[4] = {};
    for (int kc = 0; kc < 16; ++kc) {
        bf16x8 afr = *(const bf16x8*)&X[l16][kc * 32 + quad * 8];
        #pragma unroll
        for (int nt = 0; nt < 4; ++nt) {
            int col = colbase + nt * 16 + l16;
            bf16x8 bfr = *(const bf16x8*)&W4t[(size_t)col * 512 + kc * 32 + quad * 8];
            acc4[nt] = __builtin_amdgcn_mfma_f32_16x16x32_bf16(afr, bfr, acc4[nt], 0, 0, 0);
        }
    }
    // ---- epilogue: h = relu(acc + b4); out += h @ W5 ----
    float b4v[4], w5r[4][3];
    #pragma unroll
    for (int nt = 0; nt < 4; ++nt) {
        int col = colbase + nt * 16 + l16;
        b4v[nt] = b4[col];
        w5r[nt][0] = W5[col * 3 + 0];
        w5r[nt][1] = W5[col * 3 + 1];
        w5r[nt][2] = W5[col * 3 + 2];
    }
    #pragma unroll
    for (int r = 0; r < 4; ++r) {
        int row = tilebase + quad * 4 + r;
        float p0 = 0.f, p1 = 0.f, p2 = 0.f;
        #pragma unroll
        for (int nt = 0; nt < 4; ++nt) {
            float h = fmaxf(acc4[nt][r] + b4v[nt], 0.f);
            p0 += h * w5r[nt][0];
            p1 += h * w5r[nt][1];
            p2 += h * w5r[nt][2];
        }
        #pragma unroll
        for (int m = 8; m; m >>= 1) {
            p0 += __shfl_xor(p0, m);
            p1 += __shfl_xor(p1, m);
            p2 += __shfl_xor(p2, m);
        }
        if (l16 == 0) {
            atomicAdd(&out[row * 3 + 0], p0);
            atomicAdd(&out[row * 3 + 1], p1);
            atomicAdd(&out[row * 3 + 2], p2);
        }
    }
}

// ---------------- N-loop MFMA GEMM: A staged in LDS ONCE, loop over N-tiles ----------------

template<int K, int NT>
__global__ __launch_bounds__(256) void mfma_gemm_nloop_kernel(
    const unsigned short* __restrict__ A, const unsigned short* __restrict__ Bt,
    const float* __restrict__ bias, int bias_n,
    unsigned short* __restrict__ C, int M) {
    constexpr int KC = K / 32;       // k-chunks
    constexpr int N = NT * 128;
    __shared__ __align__(16) unsigned short Asl[KC][128 * 40];
    __shared__ __align__(16) unsigned short Bsl[128 * 40];
    int tid = threadIdx.x;
    int mbase = blockIdx.x * 128;
    int wave = tid >> 6, lane = tid & 63;
    int wm = (wave >> 1) * 64, wn = (wave & 1) * 64;
    int quad = lane >> 4, l16 = lane & 15;

    // stage ALL of A once: KC*512 chunks of 16B
    #pragma unroll
    for (int c = tid; c < KC * 512; c += 256) {
        int kc = c >> 9, rem = c & 511;
        int r = rem >> 2, kk = (rem & 3) * 8;
        uint4 va = make_uint4(0u, 0u, 0u, 0u);
        int gr = mbase + r;
        if (gr < M) va = *(const uint4*)&A[(size_t)gr * K + kc * 32 + kk];
        *(uint4*)&Asl[kc][r * 40 + kk] = va;
    }

    for (int nt = 0; nt < NT; ++nt) {
        int nbase = nt * 128;
        f32x4 acc[4][4] = {};
        for (int kc = 0; kc < KC; ++kc) {
            __syncthreads();
            #pragma unroll
            for (int h = 0; h < 2; ++h) {
                int c = tid + h * 256;
                int r = c >> 2, kk = (c & 3) * 8;
                uint4 vb = *(const uint4*)&Bt[(size_t)(nbase + r) * K + kc * 32 + kk];
                *(uint4*)&Bsl[r * 40 + kk] = vb;
            }
            __syncthreads();
            bf16x8 af[4], bfr[4];
            #pragma unroll
            for (int tt = 0; tt < 4; ++tt) {
                af[tt]  = *(const bf16x8*)&Asl[kc][(wm + tt * 16 + l16) * 40 + quad * 8];
                bfr[tt] = *(const bf16x8*)&Bsl[(wn + tt * 16 + l16) * 40 + quad * 8];
            }
            #pragma unroll
            for (int mt = 0; mt < 4; ++mt)
                #pragma unroll
                for (int ntt = 0; ntt < 4; ++ntt)
                    acc[mt][ntt] = __builtin_amdgcn_mfma_f32_16x16x32_bf16(
                        af[mt], bfr[ntt], acc[mt][ntt], 0, 0, 0);
        }
        #pragma unroll
        for (int mt = 0; mt < 4; ++mt) {
            #pragma unroll
            for (int r = 0; r < 4; ++r) {
                int row = mbase + wm + mt * 16 + quad * 4 + r;
                if (row >= M) continue;
                #pragma unroll
                for (int ntt = 0; ntt < 4; ++ntt) {
                    int col = nbase + wn + ntt * 16 + l16;
                    float v = acc[mt][ntt][r];
                    if (col < bias_n) v += bias[col];
                    C[(size_t)row * N + col] = f2bf(v);
                }
            }
        }
    }
}

__global__ void fallback_copy_kernel(const float* __restrict__ x, float* __restrict__ out) {
    int t = blockIdx.x * blockDim.x + threadIdx.x;
    if (t < NN * 3) out[t] = x[t];
}

// ---------------- launcher ----------------

extern "C" void kernel_launch(void* const* d_in, const int* in_sizes, int n_in,
                              void* d_out, int out_size, void* d_ws, size_t ws_size,
                              hipStream_t stream) {
    const float* x  = (const float*)d_in[0];
    const int*   ei = (const int*)d_in[1];
    const float* W1 = (const float*)d_in[2];
    const float* b1 = (const float*)d_in[3];
    const float* W2 = (const float*)d_in[4];
    const float* b2 = (const float*)d_in[5];
    const float* W3 = (const float*)d_in[6];
    const float* b3 = (const float*)d_in[7];
    const float* W4 = (const float*)d_in[8];
    const float* b4 = (const float*)d_in[9];
    const float* W5 = (const float*)d_in[10];
    const float* b5 = (const float*)d_in[11];
    float* out = (float*)d_out;

    char* p = (char*)d_ws;
    auto alloc = [&](size_t bytes) -> void* {
        void* r = (void*)p;
        p += (bytes + 255) & ~(size_t)255;
        return r;
    };
    int* deg      = (int*)alloc((size_t)NN * 4);
    int* rowstart = (int*)alloc((size_t)(NN + 1) * 4);
    int* cursor   = (int*)alloc((size_t)NN * 4);
    int* csr      = (int*)alloc((size_t)NE * 4);
    unsigned short* Bt2 = (unsigned short*)alloc(256 * 64 * 2);
    unsigned short* Bt3 = (unsigned short*)alloc(1024 * 128 * 2);
    unsigned short* W4t = (unsigned short*)alloc(256 * 512 * 2);
    unsigned short* x1 = (unsigned short*)alloc((size_t)NN * 64 * 2);
    unsigned short* x2 = (unsigned short*)alloc((size_t)NN * 128 * 2);
    unsigned short* as_slab = (unsigned short*)alloc((size_t)NN * 1024 * 2);  // as1/as2/as3
    size_t need = (size_t)(p - (char*)d_ws);
    if (ws_size < need) {
        fallback_copy_kernel<<<(NN * 3 + 255) / 256, 256, 0, stream>>>(x, out);
        return;
    }

    const int* src = ei;        // edge_index[0]
    const int* dst = ei + NE;   // edge_index[1]

    // merged setup (one dispatch)
    constexpr int SETUP_T = NN * 128 + NN * 3 + NN + NN + 8192 + 65536 + 131072;
    setup_kernel<<<(SETUP_T + 255) / 256, 256, 0, stream>>>(
        x, W1, b1, b5, W2, W3, W4, as_slab, out, deg, cursor, Bt2, Bt3, W4t);

    // CSR by dst (graph static across all 3 convs)
    hist_kernel<<<(NE + 255) / 256, 256, 0, stream>>>(dst, deg);
    scan_kernel<<<1, 1024, 0, stream>>>(deg, rowstart);
    scatter_kernel<<<(NE + 255) / 256, 256, 0, stream>>>(src, dst, rowstart, cursor, csr);

    // conv1: x1 = relu(a1 + max_j s1[j])
    edge_fused_conv1_kernel<<<12500, 256, 0, stream>>>(as_slab, rowstart, csr, x1);

    // conv2: as2 = x1 @ [Wtb2|Wb2] (+b2 on a-half); x2 = relu(a2 + max s2)
    mfma_gemm_nloop_kernel<64, 2><<<391, 256, 0, stream>>>(
        x1, Bt2, b2, 128, as_slab, NN);
    edge_fused128_kernel<<<12500, 256, 0, stream>>>(as_slab, rowstart, csr, x2);

    // conv3: as3 = x2 @ [Wtb3|Wb3] (+b3 on a-half)
    mfma_gemm_nloop_kernel<128, 8><<<391, 256, 0, stream>>>(
        x2, Bt3, b3, 512, as_slab, NN);

    // fused: paired gather -> x3 tile in LDS -> h = relu(X@W4+b4) -> out += h@W5
    ef512_w5_kernel<<<NN / 16, 256, 0, stream>>>(
        as_slab, rowstart, csr, W4t, b4, W5, out);
}

// Round 15
// 606.768 us; speedup vs baseline: 1.4120x; 1.0279x over previous
//
#include <hip/hip_runtime.h>

static constexpr int NN = 50000;
static constexpr int NE = 1000000;

typedef short bf16x8 __attribute__((ext_vector_type(8)));
typedef float f32x4 __attribute__((ext_vector_type(4)));

__device__ inline float bf2f_raw(unsigned short u) {
    return __uint_as_float(((unsigned int)u) << 16);
}
__device__ inline unsigned short f2bf(float f) {
    unsigned int u = __float_as_uint(f);
    u += 0x7fffu + ((u >> 16) & 1u);
    return (unsigned short)(u >> 16);
}
__device__ inline void fmax2(float& a0, float& a1, unsigned int v) {
    a0 = fmaxf(a0, bf2f_raw((unsigned short)(v & 0xffffu)));
    a1 = fmaxf(a1, bf2f_raw((unsigned short)(v >> 16)));
}
__device__ inline unsigned int pack2(float f0, float f1) {
    return (unsigned int)f2bf(f0) | ((unsigned int)f2bf(f1) << 16);
}
__device__ inline unsigned int addrelu2(unsigned int a, float t0, float t1) {
    float f0 = fmaxf(bf2f_raw((unsigned short)(a & 0xffffu)) + t0, 0.f);
    float f1 = fmaxf(bf2f_raw((unsigned short)(a >> 16)) + t1, 0.f);
    return pack2(f0, f1);
}

// ---------------- merged setup: conv1_as + out-init + deg-zero + cursor-zero + weight prep --------

__global__ void setup_kernel(const float* __restrict__ x, const float* __restrict__ W1,
                             const float* __restrict__ b1, const float* __restrict__ b5,
                             const float* __restrict__ W2, const float* __restrict__ W3,
                             const float* __restrict__ W4,
                             unsigned short* __restrict__ as1, float* __restrict__ out,
                             int* __restrict__ deg, int* __restrict__ cursor,
                             unsigned short* __restrict__ Bt2,
                             unsigned short* __restrict__ Bt3,
                             unsigned short* __restrict__ W4t) {
    int t = blockIdx.x * blockDim.x + threadIdx.x;
    if (t < NN * 128) {
        // conv1: as1[i] = [a1(64) | s1(64)],  a = x@(Wt-Wb)+b1, s = x@Wb  (W1 is [6][64])
        int i = t >> 7, c = t & 127;
        float x0 = x[i * 3 + 0], x1 = x[i * 3 + 1], x2 = x[i * 3 + 2];
        float v;
        if (c < 64) {
            v = x0 * (W1[c] - W1[192 + c]) + x1 * (W1[64 + c] - W1[256 + c]) +
                x2 * (W1[128 + c] - W1[320 + c]) + b1[c];
        } else {
            int cs = c - 64;
            v = x0 * W1[192 + cs] + x1 * W1[256 + cs] + x2 * W1[320 + cs];
        }
        as1[t] = f2bf(v);
        return;
    }
    t -= NN * 128;
    if (t < NN * 3) { out[t] = x[t] + b5[t % 3]; return; }
    t -= NN * 3;
    if (t < NN) { deg[t] = 0; return; }
    t -= NN;
    if (t < NN) { cursor[t] = 0; return; }
    t -= NN;
    if (t < 8192) {  // W2 split (64x128)
        int k = t / 128, c = t % 128;
        float wt = W2[k * 128 + c];
        float wb = W2[(64 + k) * 128 + c];
        Bt2[c * 64 + k] = f2bf(wt - wb);
        Bt2[(128 + c) * 64 + k] = f2bf(wb);
        return;
    }
    t -= 8192;
    if (t < 65536) {  // W3 split (128x512)
        int k = t / 512, c = t % 512;
        float wt = W3[k * 512 + c];
        float wb = W3[(128 + k) * 512 + c];
        Bt3[c * 128 + k] = f2bf(wt - wb);
        Bt3[(512 + c) * 128 + k] = f2bf(wb);
        return;
    }
    t -= 65536;
    if (t < 131072) {  // W4 transpose (512x256)
        int k = t / 256, n = t % 256;
        W4t[n * 512 + k] = f2bf(W4[k * 256 + n]);
    }
}

// ---------------- CSR build ----------------

__global__ void hist_kernel(const int* __restrict__ dst, int* __restrict__ deg) {
    int e = blockIdx.x * blockDim.x + threadIdx.x;
    if (e < NE) atomicAdd(&deg[dst[e]], 1);
}

// single-block scan, register-resident
__global__ __launch_bounds__(1024) void scan_kernel(const int* __restrict__ deg,
                                                    int* __restrict__ rowstart) {
    __shared__ int wave_sums[16];
    constexpr int CH = (NN + 1023) / 1024;  // 49
    int tid = threadIdx.x;
    int lane = tid & 63;
    int wave = tid >> 6;
    int base = tid * CH;
    int vals[CH];
    int sum = 0;
    #pragma unroll
    for (int i = 0; i < CH; ++i) {
        int idx = base + i;
        vals[i] = (idx < NN) ? deg[idx] : 0;
        sum += vals[i];
    }
    int x = sum;
    #pragma unroll
    for (int off = 1; off < 64; off <<= 1) {
        int y = __shfl_up(x, off);
        if (lane >= off) x += y;
    }
    if (lane == 63) wave_sums[wave] = x;
    __syncthreads();
    if (wave == 0 && lane < 16) {
        int s = wave_sums[lane];
        #pragma unroll
        for (int off = 1; off < 16; off <<= 1) {
            int y = __shfl_up(s, off);
            if (lane >= off) s += y;
        }
        wave_sums[lane] = s;
    }
    __syncthreads();
    int run = (wave ? wave_sums[wave - 1] : 0) + x - sum;
    #pragma unroll
    for (int i = 0; i < CH; ++i) {
        int idx = base + i;
        if (idx < NN) rowstart[idx] = run;
        run += vals[i];
    }
    if (tid == 1023) rowstart[NN] = run;
}

__global__ void scatter_kernel(const int* __restrict__ src, const int* __restrict__ dst,
                               const int* __restrict__ rowstart, int* __restrict__ cursor,
                               int* __restrict__ csr) {
    int e = blockIdx.x * blockDim.x + threadIdx.x;
    if (e < NE) {
        int d = dst[e];
        int pos = atomicAdd(&cursor[d], 1);
        csr[rowstart[d] + pos] = src[e];
    }
}

// ---------------- conv1 fused edge-max + epilogue (C=64, as rows [a(64)|s(64)]) ----------------

__global__ __launch_bounds__(256) void edge_fused_conv1_kernel(
    const unsigned short* __restrict__ as, const int* __restrict__ rowstart,
    const int* __restrict__ csr, unsigned short* __restrict__ x1) {
    int wid = (blockIdx.x * 256 + threadIdx.x) >> 6;
    int lane = threadIdx.x & 63;
    if (wid >= NN) return;
    int e0 = __builtin_amdgcn_readfirstlane(rowstart[wid]);
    int e1 = __builtin_amdgcn_readfirstlane(rowstart[wid + 1]);
    int h = lane >> 5, c0 = (lane & 31) * 2;
    float t0 = -INFINITY, t1 = -INFINITY;
    const unsigned short* sb = as + 64 + c0;
    int nedge = e1 - e0;
    for (int base = 0; base < nedge; base += 64) {
        int rem = nedge - base;
        int myj = csr[(lane < rem) ? (e0 + base + lane) : e0];
        int cnt = rem < 64 ? rem : 64;
        int cp = (cnt + 7) & ~7;
        for (int q = 0; q < cp; q += 8) {
            int j0 = __shfl(myj, q + 0 + h);
            int j1 = __shfl(myj, q + 2 + h);
            int j2 = __shfl(myj, q + 4 + h);
            int j3 = __shfl(myj, q + 6 + h);
            unsigned int v0 = *(const unsigned int*)(sb + (size_t)j0 * 128);
            unsigned int v1 = *(const unsigned int*)(sb + (size_t)j1 * 128);
            unsigned int v2 = *(const unsigned int*)(sb + (size_t)j2 * 128);
            unsigned int v3 = *(const unsigned int*)(sb + (size_t)j3 * 128);
            fmax2(t0, t1, v0);
            fmax2(t0, t1, v1);
            fmax2(t0, t1, v2);
            fmax2(t0, t1, v3);
        }
    }
    t0 = fmaxf(t0, __shfl_xor(t0, 32));
    t1 = fmaxf(t1, __shfl_xor(t1, 32));
    if (h == 0) {
        unsigned int av = *(const unsigned int*)(as + (size_t)wid * 128 + c0);
        *(unsigned int*)(x1 + (size_t)wid * 64 + c0) = addrelu2(av, t0, t1);
    }
}

// ---------------- fused edge-max + epilogue, C=128 (as rows [a(128)|s(128)]) ----------------

__global__ __launch_bounds__(256) void edge_fused128_kernel(
    const unsigned short* __restrict__ as, const int* __restrict__ rowstart,
    const int* __restrict__ csr, unsigned short* __restrict__ xout) {
    int wid = (blockIdx.x * 256 + threadIdx.x) >> 6;
    int lane = threadIdx.x & 63;
    if (wid >= NN) return;
    int e0 = __builtin_amdgcn_readfirstlane(rowstart[wid]);
    int e1 = __builtin_amdgcn_readfirstlane(rowstart[wid + 1]);
    float t0 = -INFINITY, t1 = -INFINITY;
    const unsigned short* sb = as + 128 + (size_t)lane * 2;
    int nedge = e1 - e0;
    for (int base = 0; base < nedge; base += 64) {
        int rem = nedge - base;
        int myj = csr[(lane < rem) ? (e0 + base + lane) : e0];
        int cnt = rem < 64 ? rem : 64;
        int cp = (cnt + 7) & ~7;
        for (int q = 0; q < cp; q += 8) {
            int j0 = __shfl(myj, q + 0), j1 = __shfl(myj, q + 1);
            int j2 = __shfl(myj, q + 2), j3 = __shfl(myj, q + 3);
            int j4 = __shfl(myj, q + 4), j5 = __shfl(myj, q + 5);
            int j6 = __shfl(myj, q + 6), j7 = __shfl(myj, q + 7);
            unsigned int v0 = *(const unsigned int*)(sb + (size_t)j0 * 256);
            unsigned int v1 = *(const unsigned int*)(sb + (size_t)j1 * 256);
            unsigned int v2 = *(const unsigned int*)(sb + (size_t)j2 * 256);
            unsigned int v3 = *(const unsigned int*)(sb + (size_t)j3 * 256);
            unsigned int v4 = *(const unsigned int*)(sb + (size_t)j4 * 256);
            unsigned int v5 = *(const unsigned int*)(sb + (size_t)j5 * 256);
            unsigned int v6 = *(const unsigned int*)(sb + (size_t)j6 * 256);
            unsigned int v7 = *(const unsigned int*)(sb + (size_t)j7 * 256);
            fmax2(t0, t1, v0); fmax2(t0, t1, v1);
            fmax2(t0, t1, v2); fmax2(t0, t1, v3);
            fmax2(t0, t1, v4); fmax2(t0, t1, v5);
            fmax2(t0, t1, v6); fmax2(t0, t1, v7);
        }
    }
    unsigned int av = *(const unsigned int*)(as + (size_t)wid * 256 + lane * 2);
    *(unsigned int*)(xout + (size_t)wid * 128 + lane * 2) = addrelu2(av, t0, t1);
}

// ---------------- fused ef512 + h4-GEMM + W5 (256 thr, 4 waves x 4 serial nodes) ----------------
// R11 structure (best known). av prefetched before the edge loop so the a-row load
// overlaps the gather instead of serializing after the final fmax drain.

__global__ __launch_bounds__(256) void ef512_w5_kernel(
    const unsigned short* __restrict__ as, const int* __restrict__ rowstart,
    const int* __restrict__ csr, const unsigned short* __restrict__ W4t,
    const float* __restrict__ b4, const float* __restrict__ W5,
    float* __restrict__ out) {
    __shared__ __align__(16) unsigned short X[16][520];  // x3 tile, +8 pad
    int wave = threadIdx.x >> 6, lane = threadIdx.x & 63;
    int tilebase = blockIdx.x * 16;

    // ---- gather phase: this wave builds rows wave*4 .. wave*4+3 ----
    const unsigned short* sb = as + 512 + (size_t)lane * 8;
    for (int i = 0; i < 4; ++i) {
        int node = tilebase + wave * 4 + i;
        int e0 = __builtin_amdgcn_readfirstlane(rowstart[node]);
        int e1 = __builtin_amdgcn_readfirstlane(rowstart[node + 1]);
        uint4 av = *(const uint4*)(as + (size_t)node * 1024 + lane * 8);  // prefetch a-row
        float acc[8];
        #pragma unroll
        for (int v = 0; v < 8; ++v) acc[v] = -INFINITY;
        int nedge = e1 - e0;
        for (int base = 0; base < nedge; base += 64) {
            int rem = nedge - base;
            int myj = csr[(lane < rem) ? (e0 + base + lane) : e0];
            int cnt = rem < 64 ? rem : 64;
            int cp = (cnt + 3) & ~3;
            for (int q = 0; q < cp; q += 4) {
                int j0 = __shfl(myj, q + 0), j1 = __shfl(myj, q + 1);
                int j2 = __shfl(myj, q + 2), j3 = __shfl(myj, q + 3);
                uint4 v0 = *(const uint4*)(sb + (size_t)j0 * 1024);
                uint4 v1 = *(const uint4*)(sb + (size_t)j1 * 1024);
                uint4 v2 = *(const uint4*)(sb + (size_t)j2 * 1024);
                uint4 v3 = *(const uint4*)(sb + (size_t)j3 * 1024);
                fmax2(acc[0], acc[1], v0.x); fmax2(acc[2], acc[3], v0.y);
                fmax2(acc[4], acc[5], v0.z); fmax2(acc[6], acc[7], v0.w);
                fmax2(acc[0], acc[1], v1.x); fmax2(acc[2], acc[3], v1.y);
                fmax2(acc[4], acc[5], v1.z); fmax2(acc[6], acc[7], v1.w);
                fmax2(acc[0], acc[1], v2.x); fmax2(acc[2], acc[3], v2.y);
                fmax2(acc[4], acc[5], v2.z); fmax2(acc[6], acc[7], v2.w);
                fmax2(acc[0], acc[1], v3.x); fmax2(acc[2], acc[3], v3.y);
                fmax2(acc[4], acc[5], v3.z); fmax2(acc[6], acc[7], v3.w);
            }
        }
        uint4 o;
        o.x = addrelu2(av.x, acc[0], acc[1]);
        o.y = addrelu2(av.y, acc[2], acc[3]);
        o.z = addrelu2(av.z, acc[4], acc[5]);
        o.w = addrelu2(av.w, acc[6], acc[7]);
        *(uint4*)&X[wave * 4 + i][lane * 8] = o;
    }
    __syncthreads();

    // ---- MFMA phase: wave handles cols [wave*64, wave*64+64) of h (N=256) ----
    int quad = lane >> 4, l16 = lane & 15;
    int colbase = wave * 64;
    f32x4 acc4[4] = {};
    for (int kc = 0; kc < 16; ++kc) {
        bf16x8 afr = *(const bf16x8*)&X[l16][kc * 32 + quad * 8];
        #pragma unroll
        for (int nt = 0; nt < 4; ++nt) {
            int col = colbase + nt * 16 + l16;
            bf16x8 bfr = *(const bf16x8*)&W4t[(size_t)col * 512 + kc * 32 + quad * 8];
            acc4[nt] = __builtin_amdgcn_mfma_f32_16x16x32_bf16(afr, bfr, acc4[nt], 0, 0, 0);
        }
    }
    // ---- epilogue: h = relu(acc + b4); out += h @ W5 ----
    float b4v[4], w5r[4][3];
    #pragma unroll
    for (int nt = 0; nt < 4; ++nt) {
        int col = colbase + nt * 16 + l16;
        b4v[nt] = b4[col];
        w5r[nt][0] = W5[col * 3 + 0];
        w5r[nt][1] = W5[col * 3 + 1];
        w5r[nt][2] = W5[col * 3 + 2];
    }
    #pragma unroll
    for (int r = 0; r < 4; ++r) {
        int row = tilebase + quad * 4 + r;
        float p0 = 0.f, p1 = 0.f, p2 = 0.f;
        #pragma unroll
        for (int nt = 0; nt < 4; ++nt) {
            float h = fmaxf(acc4[nt][r] + b4v[nt], 0.f);
            p0 += h * w5r[nt][0];
            p1 += h * w5r[nt][1];
            p2 += h * w5r[nt][2];
        }
        #pragma unroll
        for (int m = 8; m; m >>= 1) {
            p0 += __shfl_xor(p0, m);
            p1 += __shfl_xor(p1, m);
            p2 += __shfl_xor(p2, m);
        }
        if (l16 == 0) {
            atomicAdd(&out[row * 3 + 0], p0);
            atomicAdd(&out[row * 3 + 1], p1);
            atomicAdd(&out[row * 3 + 2], p2);
        }
    }
}

// ---------------- N-loop MFMA GEMM: A staged in LDS ONCE, loop over N-tiles ----------------

template<int K, int NT>
__global__ __launch_bounds__(256) void mfma_gemm_nloop_kernel(
    const unsigned short* __restrict__ A, const unsigned short* __restrict__ Bt,
    const float* __restrict__ bias, int bias_n,
    unsigned short* __restrict__ C, int M) {
    constexpr int KC = K / 32;       // k-chunks
    constexpr int N = NT * 128;
    __shared__ __align__(16) unsigned short Asl[KC][128 * 40];
    __shared__ __align__(16) unsigned short Bsl[128 * 40];
    int tid = threadIdx.x;
    int mbase = blockIdx.x * 128;
    int wave = tid >> 6, lane = tid & 63;
    int wm = (wave >> 1) * 64, wn = (wave & 1) * 64;
    int quad = lane >> 4, l16 = lane & 15;

    // stage ALL of A once: KC*512 chunks of 16B
    #pragma unroll
    for (int c = tid; c < KC * 512; c += 256) {
        int kc = c >> 9, rem = c & 511;
        int r = rem >> 2, kk = (rem & 3) * 8;
        uint4 va = make_uint4(0u, 0u, 0u, 0u);
        int gr = mbase + r;
        if (gr < M) va = *(const uint4*)&A[(size_t)gr * K + kc * 32 + kk];
        *(uint4*)&Asl[kc][r * 40 + kk] = va;
    }

    for (int nt = 0; nt < NT; ++nt) {
        int nbase = nt * 128;
        f32x4 acc[4][4] = {};
        for (int kc = 0; kc < KC; ++kc) {
            __syncthreads();
            #pragma unroll
            for (int h = 0; h < 2; ++h) {
                int c = tid + h * 256;
                int r = c >> 2, kk = (c & 3) * 8;
                uint4 vb = *(const uint4*)&Bt[(size_t)(nbase + r) * K + kc * 32 + kk];
                *(uint4*)&Bsl[r * 40 + kk] = vb;
            }
            __syncthreads();
            bf16x8 af[4], bfr[4];
            #pragma unroll
            for (int tt = 0; tt < 4; ++tt) {
                af[tt]  = *(const bf16x8*)&Asl[kc][(wm + tt * 16 + l16) * 40 + quad * 8];
                bfr[tt] = *(const bf16x8*)&Bsl[(wn + tt * 16 + l16) * 40 + quad * 8];
            }
            #pragma unroll
            for (int mt = 0; mt < 4; ++mt)
                #pragma unroll
                for (int ntt = 0; ntt < 4; ++ntt)
                    acc[mt][ntt] = __builtin_amdgcn_mfma_f32_16x16x32_bf16(
                        af[mt], bfr[ntt], acc[mt][ntt], 0, 0, 0);
        }
        #pragma unroll
        for (int mt = 0; mt < 4; ++mt) {
            #pragma unroll
            for (int r = 0; r < 4; ++r) {
                int row = mbase + wm + mt * 16 + quad * 4 + r;
                if (row >= M) continue;
                #pragma unroll
                for (int ntt = 0; ntt < 4; ++ntt) {
                    int col = nbase + wn + ntt * 16 + l16;
                    float v = acc[mt][ntt][r];
                    if (col < bias_n) v += bias[col];
                    C[(size_t)row * N + col] = f2bf(v);
                }
            }
        }
    }
}

__global__ void fallback_copy_kernel(const float* __restrict__ x, float* __restrict__ out) {
    int t = blockIdx.x * blockDim.x + threadIdx.x;
    if (t < NN * 3) out[t] = x[t];
}

// ---------------- launcher ----------------

extern "C" void kernel_launch(void* const* d_in, const int* in_sizes, int n_in,
                              void* d_out, int out_size, void* d_ws, size_t ws_size,
                              hipStream_t stream) {
    const float* x  = (const float*)d_in[0];
    const int*   ei = (const int*)d_in[1];
    const float* W1 = (const float*)d_in[2];
    const float* b1 = (const float*)d_in[3];
    const float* W2 = (const float*)d_in[4];
    const float* b2 = (const float*)d_in[5];
    const float* W3 = (const float*)d_in[6];
    const float* b3 = (const float*)d_in[7];
    const float* W4 = (const float*)d_in[8];
    const float* b4 = (const float*)d_in[9];
    const float* W5 = (const float*)d_in[10];
    const float* b5 = (const float*)d_in[11];
    float* out = (float*)d_out;

    char* p = (char*)d_ws;
    auto alloc = [&](size_t bytes) -> void* {
        void* r = (void*)p;
        p += (bytes + 255) & ~(size_t)255;
        return r;
    };
    int* deg      = (int*)alloc((size_t)NN * 4);
    int* rowstart = (int*)alloc((size_t)(NN + 1) * 4);
    int* cursor   = (int*)alloc((size_t)NN * 4);
    int* csr      = (int*)alloc((size_t)NE * 4);
    unsigned short* Bt2 = (unsigned short*)alloc(256 * 64 * 2);
    unsigned short* Bt3 = (unsigned short*)alloc(1024 * 128 * 2);
    unsigned short* W4t = (unsigned short*)alloc(256 * 512 * 2);
    unsigned short* x1 = (unsigned short*)alloc((size_t)NN * 64 * 2);
    unsigned short* x2 = (unsigned short*)alloc((size_t)NN * 128 * 2);
    unsigned short* as_slab = (unsigned short*)alloc((size_t)NN * 1024 * 2);  // as1/as2/as3
    size_t need = (size_t)(p - (char*)d_ws);
    if (ws_size < need) {
        fallback_copy_kernel<<<(NN * 3 + 255) / 256, 256, 0, stream>>>(x, out);
        return;
    }

    const int* src = ei;        // edge_index[0]
    const int* dst = ei + NE;   // edge_index[1]

    // merged setup (one dispatch)
    constexpr int SETUP_T = NN * 128 + NN * 3 + NN + NN + 8192 + 65536 + 131072;
    setup_kernel<<<(SETUP_T + 255) / 256, 256, 0, stream>>>(
        x, W1, b1, b5, W2, W3, W4, as_slab, out, deg, cursor, Bt2, Bt3, W4t);

    // CSR by dst (graph static across all 3 convs)
    hist_kernel<<<(NE + 255) / 256, 256, 0, stream>>>(dst, deg);
    scan_kernel<<<1, 1024, 0, stream>>>(deg, rowstart);
    scatter_kernel<<<(NE + 255) / 256, 256, 0, stream>>>(src, dst, rowstart, cursor, csr);

    // conv1: x1 = relu(a1 + max_j s1[j])
    edge_fused_conv1_kernel<<<12500, 256, 0, stream>>>(as_slab, rowstart, csr, x1);

    // conv2: as2 = x1 @ [Wtb2|Wb2] (+b2 on a-half); x2 = relu(a2 + max s2)
    mfma_gemm_nloop_kernel<64, 2><<<391, 256, 0, stream>>>(
        x1, Bt2, b2, 128, as_slab, NN);
    edge_fused128_kernel<<<12500, 256, 0, stream>>>(as_slab, rowstart, csr, x2);

    // conv3: as3 = x2 @ [Wtb3|Wb3] (+b3 on a-half)
    mfma_gemm_nloop_kernel<128, 8><<<391, 256, 0, stream>>>(
        x2, Bt3, b3, 512, as_slab, NN);

    // fused: x3 tile in LDS -> h = relu(X@W4+b4) -> out += h@W5  (x3 never hits HBM)
    ef512_w5_kernel<<<NN / 16, 256, 0, stream>>>(
        as_slab, rowstart, csr, W4t, b4, W5, out);
}

// Round 16
// 592.711 us; speedup vs baseline: 1.4455x; 1.0237x over previous
//
#include <hip/hip_runtime.h>

static constexpr int NN = 50000;
static constexpr int NE = 1000000;

typedef short bf16x8 __attribute__((ext_vector_type(8)));
typedef float f32x4 __attribute__((ext_vector_type(4)));

__device__ inline float bf2f_raw(unsigned short u) {
    return __uint_as_float(((unsigned int)u) << 16);
}
__device__ inline unsigned short f2bf(float f) {
    unsigned int u = __float_as_uint(f);
    u += 0x7fffu + ((u >> 16) & 1u);
    return (unsigned short)(u >> 16);
}
__device__ inline void fmax2(float& a0, float& a1, unsigned int v) {
    a0 = fmaxf(a0, bf2f_raw((unsigned short)(v & 0xffffu)));
    a1 = fmaxf(a1, bf2f_raw((unsigned short)(v >> 16)));
}
__device__ inline unsigned int pack2(float f0, float f1) {
    return (unsigned int)f2bf(f0) | ((unsigned int)f2bf(f1) << 16);
}
__device__ inline unsigned int addrelu2(unsigned int a, float t0, float t1) {
    float f0 = fmaxf(bf2f_raw((unsigned short)(a & 0xffffu)) + t0, 0.f);
    float f1 = fmaxf(bf2f_raw((unsigned short)(a >> 16)) + t1, 0.f);
    return pack2(f0, f1);
}

// ---------------- merged setup: conv1_as + out-init + deg-zero + cursor-zero + weight prep --------

__global__ void setup_kernel(const float* __restrict__ x, const float* __restrict__ W1,
                             const float* __restrict__ b1, const float* __restrict__ b5,
                             const float* __restrict__ W2, const float* __restrict__ W3,
                             const float* __restrict__ W4,
                             unsigned short* __restrict__ as1, float* __restrict__ out,
                             int* __restrict__ deg, int* __restrict__ cursor,
                             unsigned short* __restrict__ Bt2,
                             unsigned short* __restrict__ Bt3,
                             unsigned short* __restrict__ W4t) {
    int t = blockIdx.x * blockDim.x + threadIdx.x;
    if (t < NN * 128) {
        // conv1: as1[i] = [a1(64) | s1(64)],  a = x@(Wt-Wb)+b1, s = x@Wb  (W1 is [6][64])
        int i = t >> 7, c = t & 127;
        float x0 = x[i * 3 + 0], x1 = x[i * 3 + 1], x2 = x[i * 3 + 2];
        float v;
        if (c < 64) {
            v = x0 * (W1[c] - W1[192 + c]) + x1 * (W1[64 + c] - W1[256 + c]) +
                x2 * (W1[128 + c] - W1[320 + c]) + b1[c];
        } else {
            int cs = c - 64;
            v = x0 * W1[192 + cs] + x1 * W1[256 + cs] + x2 * W1[320 + cs];
        }
        as1[t] = f2bf(v);
        return;
    }
    t -= NN * 128;
    if (t < NN * 3) { out[t] = x[t] + b5[t % 3]; return; }
    t -= NN * 3;
    if (t < NN) { deg[t] = 0; return; }
    t -= NN;
    if (t < NN) { cursor[t] = 0; return; }
    t -= NN;
    if (t < 8192) {  // W2 split (64x128)
        int k = t / 128, c = t % 128;
        float wt = W2[k * 128 + c];
        float wb = W2[(64 + k) * 128 + c];
        Bt2[c * 64 + k] = f2bf(wt - wb);
        Bt2[(128 + c) * 64 + k] = f2bf(wb);
        return;
    }
    t -= 8192;
    if (t < 65536) {  // W3 split (128x512)
        int k = t / 512, c = t % 512;
        float wt = W3[k * 512 + c];
        float wb = W3[(128 + k) * 512 + c];
        Bt3[c * 128 + k] = f2bf(wt - wb);
        Bt3[(512 + c) * 128 + k] = f2bf(wb);
        return;
    }
    t -= 65536;
    if (t < 131072) {  // W4 transpose (512x256)
        int k = t / 256, n = t % 256;
        W4t[n * 512 + k] = f2bf(W4[k * 256 + n]);
    }
}

// ---------------- CSR build ----------------

__global__ void hist_kernel(const int* __restrict__ dst, int* __restrict__ deg) {
    int e = blockIdx.x * blockDim.x + threadIdx.x;
    if (e < NE) atomicAdd(&deg[dst[e]], 1);
}

// single-block scan, register-resident
__global__ __launch_bounds__(1024) void scan_kernel(const int* __restrict__ deg,
                                                    int* __restrict__ rowstart) {
    __shared__ int wave_sums[16];
    constexpr int CH = (NN + 1023) / 1024;  // 49
    int tid = threadIdx.x;
    int lane = tid & 63;
    int wave = tid >> 6;
    int base = tid * CH;
    int vals[CH];
    int sum = 0;
    #pragma unroll
    for (int i = 0; i < CH; ++i) {
        int idx = base + i;
        vals[i] = (idx < NN) ? deg[idx] : 0;
        sum += vals[i];
    }
    int x = sum;
    #pragma unroll
    for (int off = 1; off < 64; off <<= 1) {
        int y = __shfl_up(x, off);
        if (lane >= off) x += y;
    }
    if (lane == 63) wave_sums[wave] = x;
    __syncthreads();
    if (wave == 0 && lane < 16) {
        int s = wave_sums[lane];
        #pragma unroll
        for (int off = 1; off < 16; off <<= 1) {
            int y = __shfl_up(s, off);
            if (lane >= off) s += y;
        }
        wave_sums[lane] = s;
    }
    __syncthreads();
    int run = (wave ? wave_sums[wave - 1] : 0) + x - sum;
    #pragma unroll
    for (int i = 0; i < CH; ++i) {
        int idx = base + i;
        if (idx < NN) rowstart[idx] = run;
        run += vals[i];
    }
    if (tid == 1023) rowstart[NN] = run;
}

__global__ void scatter_kernel(const int* __restrict__ src, const int* __restrict__ dst,
                               const int* __restrict__ rowstart, int* __restrict__ cursor,
                               int* __restrict__ csr) {
    int e = blockIdx.x * blockDim.x + threadIdx.x;
    if (e < NE) {
        int d = dst[e];
        int pos = atomicAdd(&cursor[d], 1);
        csr[rowstart[d] + pos] = src[e];
    }
}

// ---------------- conv1 fused edge-max + epilogue (C=64, as rows [a(64)|s(64)]) ----------------

__global__ __launch_bounds__(256) void edge_fused_conv1_kernel(
    const unsigned short* __restrict__ as, const int* __restrict__ rowstart,
    const int* __restrict__ csr, unsigned short* __restrict__ x1) {
    int wid = (blockIdx.x * 256 + threadIdx.x) >> 6;
    int lane = threadIdx.x & 63;
    if (wid >= NN) return;
    int e0 = __builtin_amdgcn_readfirstlane(rowstart[wid]);
    int e1 = __builtin_amdgcn_readfirstlane(rowstart[wid + 1]);
    int h = lane >> 5, c0 = (lane & 31) * 2;
    float t0 = -INFINITY, t1 = -INFINITY;
    const unsigned short* sb = as + 64 + c0;
    int nedge = e1 - e0;
    for (int base = 0; base < nedge; base += 64) {
        int rem = nedge - base;
        int myj = csr[(lane < rem) ? (e0 + base + lane) : e0];
        int cnt = rem < 64 ? rem : 64;
        int cp = (cnt + 7) & ~7;
        for (int q = 0; q < cp; q += 8) {
            int j0 = __shfl(myj, q + 0 + h);
            int j1 = __shfl(myj, q + 2 + h);
            int j2 = __shfl(myj, q + 4 + h);
            int j3 = __shfl(myj, q + 6 + h);
            unsigned int v0 = *(const unsigned int*)(sb + (size_t)j0 * 128);
            unsigned int v1 = *(const unsigned int*)(sb + (size_t)j1 * 128);
            unsigned int v2 = *(const unsigned int*)(sb + (size_t)j2 * 128);
            unsigned int v3 = *(const unsigned int*)(sb + (size_t)j3 * 128);
            fmax2(t0, t1, v0);
            fmax2(t0, t1, v1);
            fmax2(t0, t1, v2);
            fmax2(t0, t1, v3);
        }
    }
    t0 = fmaxf(t0, __shfl_xor(t0, 32));
    t1 = fmaxf(t1, __shfl_xor(t1, 32));
    if (h == 0) {
        unsigned int av = *(const unsigned int*)(as + (size_t)wid * 128 + c0);
        *(unsigned int*)(x1 + (size_t)wid * 64 + c0) = addrelu2(av, t0, t1);
    }
}

// ---------------- fused edge-max + epilogue, C=128 (as rows [a(128)|s(128)]) ----------------

__global__ __launch_bounds__(256) void edge_fused128_kernel(
    const unsigned short* __restrict__ as, const int* __restrict__ rowstart,
    const int* __restrict__ csr, unsigned short* __restrict__ xout) {
    int wid = (blockIdx.x * 256 + threadIdx.x) >> 6;
    int lane = threadIdx.x & 63;
    if (wid >= NN) return;
    int e0 = __builtin_amdgcn_readfirstlane(rowstart[wid]);
    int e1 = __builtin_amdgcn_readfirstlane(rowstart[wid + 1]);
    float t0 = -INFINITY, t1 = -INFINITY;
    const unsigned short* sb = as + 128 + (size_t)lane * 2;
    int nedge = e1 - e0;
    for (int base = 0; base < nedge; base += 64) {
        int rem = nedge - base;
        int myj = csr[(lane < rem) ? (e0 + base + lane) : e0];
        int cnt = rem < 64 ? rem : 64;
        int cp = (cnt + 7) & ~7;
        for (int q = 0; q < cp; q += 8) {
            int j0 = __shfl(myj, q + 0), j1 = __shfl(myj, q + 1);
            int j2 = __shfl(myj, q + 2), j3 = __shfl(myj, q + 3);
            int j4 = __shfl(myj, q + 4), j5 = __shfl(myj, q + 5);
            int j6 = __shfl(myj, q + 6), j7 = __shfl(myj, q + 7);
            unsigned int v0 = *(const unsigned int*)(sb + (size_t)j0 * 256);
            unsigned int v1 = *(const unsigned int*)(sb + (size_t)j1 * 256);
            unsigned int v2 = *(const unsigned int*)(sb + (size_t)j2 * 256);
            unsigned int v3 = *(const unsigned int*)(sb + (size_t)j3 * 256);
            unsigned int v4 = *(const unsigned int*)(sb + (size_t)j4 * 256);
            unsigned int v5 = *(const unsigned int*)(sb + (size_t)j5 * 256);
            unsigned int v6 = *(const unsigned int*)(sb + (size_t)j6 * 256);
            unsigned int v7 = *(const unsigned int*)(sb + (size_t)j7 * 256);
            fmax2(t0, t1, v0); fmax2(t0, t1, v1);
            fmax2(t0, t1, v2); fmax2(t0, t1, v3);
            fmax2(t0, t1, v4); fmax2(t0, t1, v5);
            fmax2(t0, t1, v6); fmax2(t0, t1, v7);
        }
    }
    unsigned int av = *(const unsigned int*)(as + (size_t)wid * 256 + lane * 2);
    *(unsigned int*)(xout + (size_t)wid * 128 + lane * 2) = addrelu2(av, t0, t1);
}

// ---------------- fused ef512 + h4-GEMM + W5 (256 thr, 4 waves x 4 serial nodes) ----------------
// R11 exact structure — measured optimum across R11-R15 variants.

__global__ __launch_bounds__(256) void ef512_w5_kernel(
    const unsigned short* __restrict__ as, const int* __restrict__ rowstart,
    const int* __restrict__ csr, const unsigned short* __restrict__ W4t,
    const float* __restrict__ b4, const float* __restrict__ W5,
    float* __restrict__ out) {
    __shared__ __align__(16) unsigned short X[16][520];  // x3 tile, +8 pad
    int wave = threadIdx.x >> 6, lane = threadIdx.x & 63;
    int tilebase = blockIdx.x * 16;

    // ---- gather phase: this wave builds rows wave*4 .. wave*4+3 ----
    const unsigned short* sb = as + 512 + (size_t)lane * 8;
    for (int i = 0; i < 4; ++i) {
        int node = tilebase + wave * 4 + i;
        int e0 = __builtin_amdgcn_readfirstlane(rowstart[node]);
        int e1 = __builtin_amdgcn_readfirstlane(rowstart[node + 1]);
        float acc[8];
        #pragma unroll
        for (int v = 0; v < 8; ++v) acc[v] = -INFINITY;
        int nedge = e1 - e0;
        for (int base = 0; base < nedge; base += 64) {
            int rem = nedge - base;
            int myj = csr[(lane < rem) ? (e0 + base + lane) : e0];
            int cnt = rem < 64 ? rem : 64;
            int cp = (cnt + 3) & ~3;
            for (int q = 0; q < cp; q += 4) {
                int j0 = __shfl(myj, q + 0), j1 = __shfl(myj, q + 1);
                int j2 = __shfl(myj, q + 2), j3 = __shfl(myj, q + 3);
                uint4 v0 = *(const uint4*)(sb + (size_t)j0 * 1024);
                uint4 v1 = *(const uint4*)(sb + (size_t)j1 * 1024);
                uint4 v2 = *(const uint4*)(sb + (size_t)j2 * 1024);
                uint4 v3 = *(const uint4*)(sb + (size_t)j3 * 1024);
                fmax2(acc[0], acc[1], v0.x); fmax2(acc[2], acc[3], v0.y);
                fmax2(acc[4], acc[5], v0.z); fmax2(acc[6], acc[7], v0.w);
                fmax2(acc[0], acc[1], v1.x); fmax2(acc[2], acc[3], v1.y);
                fmax2(acc[4], acc[5], v1.z); fmax2(acc[6], acc[7], v1.w);
                fmax2(acc[0], acc[1], v2.x); fmax2(acc[2], acc[3], v2.y);
                fmax2(acc[4], acc[5], v2.z); fmax2(acc[6], acc[7], v2.w);
                fmax2(acc[0], acc[1], v3.x); fmax2(acc[2], acc[3], v3.y);
                fmax2(acc[4], acc[5], v3.z); fmax2(acc[6], acc[7], v3.w);
            }
        }
        uint4 av = *(const uint4*)(as + (size_t)node * 1024 + lane * 8);
        uint4 o;
        o.x = addrelu2(av.x, acc[0], acc[1]);
        o.y = addrelu2(av.y, acc[2], acc[3]);
        o.z = addrelu2(av.z, acc[4], acc[5]);
        o.w = addrelu2(av.w, acc[6], acc[7]);
        *(uint4*)&X[wave * 4 + i][lane * 8] = o;
    }
    __syncthreads();

    // ---- MFMA phase: wave handles cols [wave*64, wave*64+64) of h (N=256) ----
    int quad = lane >> 4, l16 = lane & 15;
    int colbase = wave * 64;
    f32x4 acc4[4] = {};
    for (int kc = 0; kc < 16; ++kc) {
        bf16x8 afr = *(const bf16x8*)&X[l16][kc * 32 + quad * 8];
        #pragma unroll
        for (int nt = 0; nt < 4; ++nt) {
            int col = colbase + nt * 16 + l16;
            bf16x8 bfr = *(const bf16x8*)&W4t[(size_t)col * 512 + kc * 32 + quad * 8];
            acc4[nt] = __builtin_amdgcn_mfma_f32_16x16x32_bf16(afr, bfr, acc4[nt], 0, 0, 0);
        }
    }
    // ---- epilogue: h = relu(acc + b4); out += h @ W5 ----
    float b4v[4], w5r[4][3];
    #pragma unroll
    for (int nt = 0; nt < 4; ++nt) {
        int col = colbase + nt * 16 + l16;
        b4v[nt] = b4[col];
        w5r[nt][0] = W5[col * 3 + 0];
        w5r[nt][1] = W5[col * 3 + 1];
        w5r[nt][2] = W5[col * 3 + 2];
    }
    #pragma unroll
    for (int r = 0; r < 4; ++r) {
        int row = tilebase + quad * 4 + r;
        float p0 = 0.f, p1 = 0.f, p2 = 0.f;
        #pragma unroll
        for (int nt = 0; nt < 4; ++nt) {
            float h = fmaxf(acc4[nt][r] + b4v[nt], 0.f);
            p0 += h * w5r[nt][0];
            p1 += h * w5r[nt][1];
            p2 += h * w5r[nt][2];
        }
        #pragma unroll
        for (int m = 8; m; m >>= 1) {
            p0 += __shfl_xor(p0, m);
            p1 += __shfl_xor(p1, m);
            p2 += __shfl_xor(p2, m);
        }
        if (l16 == 0) {
            atomicAdd(&out[row * 3 + 0], p0);
            atomicAdd(&out[row * 3 + 1], p1);
            atomicAdd(&out[row * 3 + 2], p2);
        }
    }
}

// ---------------- N-loop MFMA GEMM: A staged in LDS ONCE, loop over N-tiles ----------------

template<int K, int NT>
__global__ __launch_bounds__(256) void mfma_gemm_nloop_kernel(
    const unsigned short* __restrict__ A, const unsigned short* __restrict__ Bt,
    const float* __restrict__ bias, int bias_n,
    unsigned short* __restrict__ C, int M) {
    constexpr int KC = K / 32;       // k-chunks
    constexpr int N = NT * 128;
    __shared__ __align__(16) unsigned short Asl[KC][128 * 40];
    __shared__ __align__(16) unsigned short Bsl[128 * 40];
    int tid = threadIdx.x;
    int mbase = blockIdx.x * 128;
    int wave = tid >> 6, lane = tid & 63;
    int wm = (wave >> 1) * 64, wn = (wave & 1) * 64;
    int quad = lane >> 4, l16 = lane & 15;

    // stage ALL of A once: KC*512 chunks of 16B
    #pragma unroll
    for (int c = tid; c < KC * 512; c += 256) {
        int kc = c >> 9, rem = c & 511;
        int r = rem >> 2, kk = (rem & 3) * 8;
        uint4 va = make_uint4(0u, 0u, 0u, 0u);
        int gr = mbase + r;
        if (gr < M) va = *(const uint4*)&A[(size_t)gr * K + kc * 32 + kk];
        *(uint4*)&Asl[kc][r * 40 + kk] = va;
    }

    for (int nt = 0; nt < NT; ++nt) {
        int nbase = nt * 128;
        f32x4 acc[4][4] = {};
        for (int kc = 0; kc < KC; ++kc) {
            __syncthreads();
            #pragma unroll
            for (int h = 0; h < 2; ++h) {
                int c = tid + h * 256;
                int r = c >> 2, kk = (c & 3) * 8;
                uint4 vb = *(const uint4*)&Bt[(size_t)(nbase + r) * K + kc * 32 + kk];
                *(uint4*)&Bsl[r * 40 + kk] = vb;
            }
            __syncthreads();
            bf16x8 af[4], bfr[4];
            #pragma unroll
            for (int tt = 0; tt < 4; ++tt) {
                af[tt]  = *(const bf16x8*)&Asl[kc][(wm + tt * 16 + l16) * 40 + quad * 8];
                bfr[tt] = *(const bf16x8*)&Bsl[(wn + tt * 16 + l16) * 40 + quad * 8];
            }
            #pragma unroll
            for (int mt = 0; mt < 4; ++mt)
                #pragma unroll
                for (int ntt = 0; ntt < 4; ++ntt)
                    acc[mt][ntt] = __builtin_amdgcn_mfma_f32_16x16x32_bf16(
                        af[mt], bfr[ntt], acc[mt][ntt], 0, 0, 0);
        }
        #pragma unroll
        for (int mt = 0; mt < 4; ++mt) {
            #pragma unroll
            for (int r = 0; r < 4; ++r) {
                int row = mbase + wm + mt * 16 + quad * 4 + r;
                if (row >= M) continue;
                #pragma unroll
                for (int ntt = 0; ntt < 4; ++ntt) {
                    int col = nbase + wn + ntt * 16 + l16;
                    float v = acc[mt][ntt][r];
                    if (col < bias_n) v += bias[col];
                    C[(size_t)row * N + col] = f2bf(v);
                }
            }
        }
    }
}

__global__ void fallback_copy_kernel(const float* __restrict__ x, float* __restrict__ out) {
    int t = blockIdx.x * blockDim.x + threadIdx.x;
    if (t < NN * 3) out[t] = x[t];
}

// ---------------- launcher ----------------

extern "C" void kernel_launch(void* const* d_in, const int* in_sizes, int n_in,
                              void* d_out, int out_size, void* d_ws, size_t ws_size,
                              hipStream_t stream) {
    const float* x  = (const float*)d_in[0];
    const int*   ei = (const int*)d_in[1];
    const float* W1 = (const float*)d_in[2];
    const float* b1 = (const float*)d_in[3];
    const float* W2 = (const float*)d_in[4];
    const float* b2 = (const float*)d_in[5];
    const float* W3 = (const float*)d_in[6];
    const float* b3 = (const float*)d_in[7];
    const float* W4 = (const float*)d_in[8];
    const float* b4 = (const float*)d_in[9];
    const float* W5 = (const float*)d_in[10];
    const float* b5 = (const float*)d_in[11];
    float* out = (float*)d_out;

    char* p = (char*)d_ws;
    auto alloc = [&](size_t bytes) -> void* {
        void* r = (void*)p;
        p += (bytes + 255) & ~(size_t)255;
        return r;
    };
    int* deg      = (int*)alloc((size_t)NN * 4);
    int* rowstart = (int*)alloc((size_t)(NN + 1) * 4);
    int* cursor   = (int*)alloc((size_t)NN * 4);
    int* csr      = (int*)alloc((size_t)NE * 4);
    unsigned short* Bt2 = (unsigned short*)alloc(256 * 64 * 2);
    unsigned short* Bt3 = (unsigned short*)alloc(1024 * 128 * 2);
    unsigned short* W4t = (unsigned short*)alloc(256 * 512 * 2);
    unsigned short* x1 = (unsigned short*)alloc((size_t)NN * 64 * 2);
    unsigned short* x2 = (unsigned short*)alloc((size_t)NN * 128 * 2);
    unsigned short* as_slab = (unsigned short*)alloc((size_t)NN * 1024 * 2);  // as1/as2/as3
    size_t need = (size_t)(p - (char*)d_ws);
    if (ws_size < need) {
        fallback_copy_kernel<<<(NN * 3 + 255) / 256, 256, 0, stream>>>(x, out);
        return;
    }

    const int* src = ei;        // edge_index[0]
    const int* dst = ei + NE;   // edge_index[1]

    // merged setup (one dispatch)
    constexpr int SETUP_T = NN * 128 + NN * 3 + NN + NN + 8192 + 65536 + 131072;
    setup_kernel<<<(SETUP_T + 255) / 256, 256, 0, stream>>>(
        x, W1, b1, b5, W2, W3, W4, as_slab, out, deg, cursor, Bt2, Bt3, W4t);

    // CSR by dst (graph static across all 3 convs)
    hist_kernel<<<(NE + 255) / 256, 256, 0, stream>>>(dst, deg);
    scan_kernel<<<1, 1024, 0, stream>>>(deg, rowstart);
    scatter_kernel<<<(NE + 255) / 256, 256, 0, stream>>>(src, dst, rowstart, cursor, csr);

    // conv1: x1 = relu(a1 + max_j s1[j])
    edge_fused_conv1_kernel<<<12500, 256, 0, stream>>>(as_slab, rowstart, csr, x1);

    // conv2: as2 = x1 @ [Wtb2|Wb2] (+b2 on a-half); x2 = relu(a2 + max s2)
    mfma_gemm_nloop_kernel<64, 2><<<391, 256, 0, stream>>>(
        x1, Bt2, b2, 128, as_slab, NN);
    edge_fused128_kernel<<<12500, 256, 0, stream>>>(as_slab, rowstart, csr, x2);

    // conv3: as3 = x2 @ [Wtb3|Wb3] (+b3 on a-half)
    mfma_gemm_nloop_kernel<128, 8><<<391, 256, 0, stream>>>(
        x2, Bt3, b3, 512, as_slab, NN);

    // fused: x3 tile in LDS -> h = relu(X@W4+b4) -> out += h@W5  (x3 never hits HBM)
    ef512_w5_kernel<<<NN / 16, 256, 0, stream>>>(
        as_slab, rowstart, csr, W4t, b4, W5, out);
}